// Round 12
// baseline (267.970 us; speedup 1.0000x reference)
//
#include <hip/hip_runtime.h>
#include <hip/hip_bf16.h>
#include <stdint.h>

#define DIMN 1024
#define N1C 32768
#define N2C 512
#define KTOP 64
#define MCAND 80
#define CAP 256
#define SEG 8192
#define SEGCAP 256

typedef unsigned short ushort_t;
typedef __attribute__((ext_vector_type(8))) short short8;
typedef __attribute__((ext_vector_type(4))) float f32x4;

__device__ __forceinline__ double wave_reduce_sum_d(double v) {
    #pragma unroll
    for (int off = 32; off > 0; off >>= 1)
        v += __shfl_down(v, off, 64);
    return v;
}

__device__ __forceinline__ unsigned wave_reduce_sum_u(unsigned v) {
    #pragma unroll
    for (int off = 32; off > 0; off >>= 1)
        v += __shfl_down(v, off, 64);
    return v;
}

__device__ __forceinline__ void gload_lds16(const void* g, void* l) {
    __builtin_amdgcn_global_load_lds(
        (const __attribute__((address_space(1))) unsigned*)g,
        (__attribute__((address_space(3))) unsigned*)l, 16, 0, 0);
}

__device__ __forceinline__ ushort_t f2bf(float f) {
    __hip_bfloat16 h = __float2bfloat16(f);
    return *reinterpret_cast<ushort_t*>(&h);
}

__device__ __forceinline__ unsigned key_of_bf16(unsigned u16) {
    return (u16 & 0x8000u) ? (0xFFFFu & ~u16) : (u16 | 0x8000u);
}

// ---------------------------------------------------------------------------
// Kernel 1: fused LN for BOTH inputs, wave-per-row, barrier-free.
// ---------------------------------------------------------------------------
__global__ __launch_bounds__(256) void ln_all(
    const float* __restrict__ prior, const float* __restrict__ clip,
    const float* __restrict__ g1, const float* __restrict__ b1,
    const float* __restrict__ g2, const float* __restrict__ b2,
    __hip_bfloat16* __restrict__ x1n, __hip_bfloat16* __restrict__ x2n,
    double* __restrict__ stats1, double* __restrict__ wq,
    double* __restrict__ consts) {
    const int bid = blockIdx.x;
    const int tid = threadIdx.x;
    const int lane = tid & 63, wave = tid >> 6;

    if (bid < N1C / 4) {
        const int row = bid * 4 + wave;
        const float* xr = prior + (size_t)row * DIMN;
        float4 xv[4], gv[4], bv[4];
        #pragma unroll
        for (int j = 0; j < 4; ++j) {
            xv[j] = *(const float4*)(xr + lane * 4 + j * 256);
            gv[j] = *(const float4*)(g1 + lane * 4 + j * 256);
            bv[j] = *(const float4*)(b1 + lane * 4 + j * 256);
        }
        double s = 0.0, s2 = 0.0;
        #pragma unroll
        for (int j = 0; j < 4; ++j) {
            double a = xv[j].x, b = xv[j].y, c = xv[j].z, d = xv[j].w;
            s += (a + b) + (c + d);
            s2 += (a * a + b * b) + (c * c + d * d);
        }
        s = wave_reduce_sum_d(s);
        s2 = wave_reduce_sum_d(s2);
        double mu, rstd;
        if (lane == 0) {
            mu = s / (double)DIMN;
            double var = s2 / (double)DIMN - mu * mu;
            rstd = 1.0 / sqrt(var + 1e-5);
        }
        mu = __shfl(mu, 0, 64);
        rstd = __shfl(rstd, 0, 64);

        double y[16];
        double q = 0.0;
        #pragma unroll
        for (int j = 0; j < 4; ++j) {
            double y0 = ((double)xv[j].x - mu) * rstd * (double)gv[j].x + (double)bv[j].x;
            double y1 = ((double)xv[j].y - mu) * rstd * (double)gv[j].y + (double)bv[j].y;
            double y2 = ((double)xv[j].z - mu) * rstd * (double)gv[j].z + (double)bv[j].z;
            double y3 = ((double)xv[j].w - mu) * rstd * (double)gv[j].w + (double)bv[j].w;
            y[j * 4 + 0] = y0; y[j * 4 + 1] = y1; y[j * 4 + 2] = y2; y[j * 4 + 3] = y3;
            q += (y0 * y0 + y1 * y1) + (y2 * y2 + y3 * y3);
        }
        q = wave_reduce_sum_d(q);
        double invn;
        if (lane == 0) {
            invn = 1.0 / fmax(sqrt(q), 1e-8);
            stats1[(size_t)row * 3 + 0] = mu;
            stats1[(size_t)row * 3 + 1] = rstd;
            stats1[(size_t)row * 3 + 2] = invn;
        }
        invn = __shfl(invn, 0, 64);

        ushort_t* dst = (ushort_t*)x1n + (size_t)row * DIMN;
        #pragma unroll
        for (int j = 0; j < 4; ++j) {
            uint2 pk;
            pk.x = (unsigned)f2bf((float)(y[j * 4 + 0] * invn)) |
                   ((unsigned)f2bf((float)(y[j * 4 + 1] * invn)) << 16);
            pk.y = (unsigned)f2bf((float)(y[j * 4 + 2] * invn)) |
                   ((unsigned)f2bf((float)(y[j * 4 + 3] * invn)) << 16);
            *(uint2*)(dst + lane * 4 + j * 256) = pk;
        }
    } else {
        const int q = (bid - N1C / 4) * 4 + wave;
        const float* xr = clip + (size_t)q * DIMN;
        float4 xv[4];
        #pragma unroll
        for (int j = 0; j < 4; ++j)
            xv[j] = *(const float4*)(xr + lane * 4 + j * 256);

        double s = 0.0, s2 = 0.0;
        #pragma unroll
        for (int j = 0; j < 4; ++j) {
            double a = xv[j].x, b = xv[j].y, c = xv[j].z, d = xv[j].w;
            s += (a + b) + (c + d);
            s2 += (a * a + b * b) + (c * c + d * d);
        }
        s = wave_reduce_sum_d(s);
        s2 = wave_reduce_sum_d(s2);
        double mu, rstd;
        if (lane == 0) {
            mu = s / (double)DIMN;
            double var = s2 / (double)DIMN - mu * mu;
            rstd = 1.0 / sqrt(var + 1e-5);
        }
        mu = __shfl(mu, 0, 64);
        rstd = __shfl(rstd, 0, 64);

        double yv[16];
        double qq = 0.0;
        #pragma unroll
        for (int j = 0; j < 4; ++j) {
            const float4 g2v = *(const float4*)(g2 + lane * 4 + j * 256);
            const float4 b2v = *(const float4*)(b2 + lane * 4 + j * 256);
            double y0 = ((double)xv[j].x - mu) * rstd * (double)g2v.x + (double)b2v.x;
            double y1 = ((double)xv[j].y - mu) * rstd * (double)g2v.y + (double)b2v.y;
            double y2 = ((double)xv[j].z - mu) * rstd * (double)g2v.z + (double)b2v.z;
            double y3 = ((double)xv[j].w - mu) * rstd * (double)g2v.w + (double)b2v.w;
            yv[j * 4 + 0] = y0; yv[j * 4 + 1] = y1;
            yv[j * 4 + 2] = y2; yv[j * 4 + 3] = y3;
            qq += (y0 * y0 + y1 * y1) + (y2 * y2 + y3 * y3);
        }
        qq = wave_reduce_sum_d(qq);
        double invn;
        if (lane == 0) invn = 1.0 / fmax(sqrt(qq), 1e-8);
        invn = __shfl(invn, 0, 64);

        double c1 = 0.0, c2 = 0.0;
        ushort_t* dst = (ushort_t*)x2n + (size_t)q * DIMN;
        double* wrow = wq + (size_t)q * DIMN;
        #pragma unroll
        for (int j = 0; j < 4; ++j) {
            double y0 = yv[j * 4 + 0] * invn, y1 = yv[j * 4 + 1] * invn;
            double y2 = yv[j * 4 + 2] * invn, y3 = yv[j * 4 + 3] * invn;
            uint2 pk;
            pk.x = (unsigned)f2bf((float)y0) | ((unsigned)f2bf((float)y1) << 16);
            pk.y = (unsigned)f2bf((float)y2) | ((unsigned)f2bf((float)y3) << 16);
            *(uint2*)(dst + lane * 4 + j * 256) = pk;

            const float4 g1v = *(const float4*)(g1 + lane * 4 + j * 256);
            const float4 b1v = *(const float4*)(b1 + lane * 4 + j * 256);
            double w0 = y0 * (double)g1v.x, w1 = y1 * (double)g1v.y;
            double w2 = y2 * (double)g1v.z, w3 = y3 * (double)g1v.w;
            double* wp = wrow + lane * 4 + j * 256;
            double2 t0; t0.x = w0; t0.y = w1;
            double2 t1; t1.x = w2; t1.y = w3;
            *(double2*)(wp) = t0;
            *(double2*)(wp + 2) = t1;
            c1 += ((double)b1v.x * y0 + (double)b1v.y * y1) +
                  ((double)b1v.z * y2 + (double)b1v.w * y3);
            c2 += (w0 + w1) + (w2 + w3);
        }
        c1 = wave_reduce_sum_d(c1);
        c2 = wave_reduce_sum_d(c2);
        if (lane == 0) {
            consts[(size_t)q * 2 + 0] = c1;
            consts[(size_t)q * 2 + 1] = c2;
        }
    }
}

// ---------------------------------------------------------------------------
// Kernel 2: candidate GEMM via MFMA (m97 structure, BK=64, XCD swizzle).
// ---------------------------------------------------------------------------
#define BM 128
#define BN 128
#define BKG 64

__global__ __launch_bounds__(256) void sim_gemm(
    const __hip_bfloat16* __restrict__ x2n, const __hip_bfloat16* __restrict__ x1n,
    ushort_t* __restrict__ simkey) {
    __shared__ ushort_t As[BM][BKG];
    __shared__ ushort_t Bs[BN][BKG];

    const int bid = blockIdx.x;
    const int l = (bid & 7) * 128 + (bid >> 3);
    const int q0 = (l & 3) * BM;
    const int n0 = (l >> 2) * BN;

    const int tid = threadIdx.x;
    const int ln = tid & 63, wv = tid >> 6;
    const int wr = wv >> 1, wc = wv & 1;

    const int st_r = ln >> 3;
    const int st_c = (ln & 7) * 8;

    const ushort_t* Ab = (const ushort_t*)x2n;
    const ushort_t* Bb = (const ushort_t*)x1n;

    f32x4 acc[4][4];
    #pragma unroll
    for (int m = 0; m < 4; ++m)
        #pragma unroll
        for (int n = 0; n < 4; ++n) acc[m][n] = (f32x4)0.0f;

    const int lr = ln & 15;
    const int lk = (ln >> 4) * 8;

    for (int kt = 0; kt < DIMN; kt += BKG) {
        #pragma unroll
        for (int i = 0; i < 4; ++i) {
            int ci = i * 4 + wv;
            int row = ci * 8 + st_r;
            gload_lds16(Ab + (size_t)(q0 + row) * DIMN + kt + st_c,
                        (char*)&As[0][0] + ci * 1024);
            gload_lds16(Bb + (size_t)(n0 + row) * DIMN + kt + st_c,
                        (char*)&Bs[0][0] + ci * 1024);
        }
        __syncthreads();

        short8 af[4][2], bfr[4][2];
        #pragma unroll
        for (int m = 0; m < 4; ++m) {
            af[m][0] = *(const short8*)&As[wr * 64 + m * 16 + lr][lk];
            af[m][1] = *(const short8*)&As[wr * 64 + m * 16 + lr][32 + lk];
        }
        #pragma unroll
        for (int n = 0; n < 4; ++n) {
            bfr[n][0] = *(const short8*)&Bs[wc * 64 + n * 16 + lr][lk];
            bfr[n][1] = *(const short8*)&Bs[wc * 64 + n * 16 + lr][32 + lk];
        }
        #pragma unroll
        for (int m = 0; m < 4; ++m)
            #pragma unroll
            for (int n = 0; n < 4; ++n) {
                acc[m][n] = __builtin_amdgcn_mfma_f32_16x16x32_bf16(
                    af[m][0], bfr[n][0], acc[m][n], 0, 0, 0);
                acc[m][n] = __builtin_amdgcn_mfma_f32_16x16x32_bf16(
                    af[m][1], bfr[n][1], acc[m][n], 0, 0, 0);
            }
        __syncthreads();
    }

    const int crow = (ln >> 4) * 4;
    #pragma unroll
    for (int m = 0; m < 4; ++m) {
        #pragma unroll
        for (int n = 0; n < 4; ++n) {
            int col = n0 + wc * 64 + n * 16 + lr;
            #pragma unroll
            for (int r = 0; r < 4; ++r) {
                int row = q0 + wr * 64 + m * 16 + crow + r;
                simkey[(size_t)row * N1C + col] =
                    (ushort_t)key_of_bf16((unsigned)f2bf(acc[m][n][r]));
            }
        }
    }
}

// ---------------------------------------------------------------------------
// Kernel 3: per-(q, segment) top->=MCAND. Grid 2048 blocks, keys in
// REGISTERS, 16 bisection passes with one LDS-atomic count + barrier each.
// ---------------------------------------------------------------------------
__global__ __launch_bounds__(256) void seg_topk_reg(
    const ushort_t* __restrict__ simkey, unsigned* __restrict__ segcand,
    int* __restrict__ segcnt) {
    const int bid = blockIdx.x;
    const int seg = bid & 3, q = bid >> 2;
    const int tid = threadIdx.x;
    const int lane = tid & 63;

    __shared__ unsigned csum[16];
    __shared__ unsigned scnt;

    if (tid < 16) csum[tid] = 0;
    if (tid == 0) scnt = 0;
    __syncthreads();

    const unsigned* rowPair =
        (const unsigned*)(simkey + (size_t)q * N1C) + seg * (SEG / 2);
    unsigned kreg[16];
    #pragma unroll
    for (int s = 0; s < 16; ++s)
        kreg[s] = rowPair[s * 256 + tid];

    unsigned lo = 0, hi = 65536;
    #pragma unroll 1
    for (int pass = 0; pass < 16; ++pass) {
        unsigned mid = (lo + hi) >> 1;
        unsigned c = 0;
        #pragma unroll
        for (int s = 0; s < 16; ++s) {
            c += ((kreg[s] & 0xFFFFu) >= mid) ? 1u : 0u;
            c += ((kreg[s] >> 16)     >= mid) ? 1u : 0u;
        }
        c = wave_reduce_sum_u(c);
        if (lane == 0) atomicAdd(&csum[pass], c);
        __syncthreads();
        if (csum[pass] >= MCAND) lo = mid; else hi = mid;
    }
    const unsigned thr_w = lo;

    #pragma unroll
    for (int s = 0; s < 16; ++s) {
        unsigned k0 = kreg[s] & 0xFFFFu, k1 = kreg[s] >> 16;
        unsigned e0 = (unsigned)(seg * SEG + (s * 256 + tid) * 2);
        if (k0 >= thr_w) {
            unsigned p = atomicAdd(&scnt, 1u);
            if (p < SEGCAP) segcand[(size_t)bid * SEGCAP + p] = (k0 << 16) | e0;
        }
        if (k1 >= thr_w) {
            unsigned p = atomicAdd(&scnt, 1u);
            if (p < SEGCAP) segcand[(size_t)bid * SEGCAP + p] = (k1 << 16) | (e0 + 1);
        }
    }
    __syncthreads();
    if (tid == 0) segcnt[bid] = (int)(scnt < SEGCAP ? scnt : SEGCAP);
}

// ---------------------------------------------------------------------------
// Kernel 4: fused tail: merge threshold + fp64 score + exact top-64.
// 512 blocks x 1024 thr (16 waves).
//  A: load <=1024 pooled entries to LDS.
//  B: wave 0 register-bisects merged threshold (shfl-only, no barriers).
//  C: all 1024 threads emit >=thr entries to LDS cand list.
//  D: 16 waves score candidates (fp64 factorized, 4-row ILP), vals in LDS.
//  E: wave 0 tournament-selects top-64 (value desc, idx asc) -> out.
// ---------------------------------------------------------------------------
__global__ __launch_bounds__(1024) void merge_score_select(
    const unsigned* __restrict__ segcand, const int* __restrict__ segcnt,
    const float* __restrict__ x1, const double* __restrict__ stats1,
    const double* __restrict__ wq, const double* __restrict__ consts,
    float* __restrict__ out) {
    const int q = blockIdx.x;
    const int tid = threadIdx.x;
    const int lane = tid & 63, wave = tid >> 6;

    __shared__ unsigned buf[4 * SEGCAP];   // 4 KB
    __shared__ int offs[5];
    __shared__ unsigned gthr;
    __shared__ unsigned gcnt;
    __shared__ int candLds[CAP];           // 1 KB
    __shared__ double valsLds[CAP];        // 2 KB

    if (tid == 0) {
        int o = 0;
        #pragma unroll
        for (int s = 0; s < 4; ++s) { offs[s] = o; o += segcnt[q * 4 + s]; }
        offs[4] = o;
        gcnt = 0;
    }
    if (tid < CAP) { valsLds[tid] = -1e300; candLds[tid] = 0x7FFFFFFF; }
    __syncthreads();
    const int tot = offs[4];
    #pragma unroll
    for (int s = 0; s < 4; ++s) {
        int cs = offs[s + 1] - offs[s];
        for (int i = tid; i < cs; i += 1024)
            buf[offs[s] + i] = segcand[(size_t)(q * 4 + s) * SEGCAP + i];
    }
    __syncthreads();

    // --- B: wave 0 register bisect over pool (barrier-free) ---
    if (wave == 0) {
        unsigned pk[16];
        #pragma unroll
        for (int j = 0; j < 16; ++j) {
            int i = j * 64 + lane;
            pk[j] = (i < tot) ? buf[i] : 0u;
        }
        unsigned lo = 0, hi = 65536;
        #pragma unroll 1
        for (int pass = 0; pass < 16; ++pass) {
            unsigned mid = (lo + hi) >> 1;
            unsigned c = 0;
            #pragma unroll
            for (int j = 0; j < 16; ++j) {
                int i = j * 64 + lane;
                c += (i < tot && (pk[j] >> 16) >= mid) ? 1u : 0u;
            }
            c = wave_reduce_sum_u(c);
            c = __shfl(c, 0, 64);
            if (c >= MCAND) lo = mid; else hi = mid;
        }
        if (lane == 0) gthr = lo;
    }
    __syncthreads();
    const unsigned thr = gthr;

    // --- C: emit candidates to LDS ---
    if (tid < (unsigned)tot) {
        unsigned b = buf[tid];
        if ((b >> 16) >= thr) {
            unsigned p = atomicAdd(&gcnt, 1u);
            if (p < CAP) candLds[p] = (int)(b & 0xFFFFu);
        }
    }
    __syncthreads();
    const int cnt = (int)(gcnt < CAP ? gcnt : CAP);

    // --- D: fp64 factorized scoring, 4-row ILP per wave ---
    const double C1 = consts[(size_t)q * 2 + 0];
    const double C2 = consts[(size_t)q * 2 + 1];
    const double* w = wq + (size_t)q * DIMN;
    double wr[16];
    #pragma unroll
    for (int j = 0; j < 4; ++j) {
        double2 a = *(const double2*)(w + lane * 4 + j * 256);
        double2 b = *(const double2*)(w + lane * 4 + j * 256 + 2);
        wr[j * 4 + 0] = a.x; wr[j * 4 + 1] = a.y;
        wr[j * 4 + 2] = b.x; wr[j * 4 + 3] = b.y;
    }

    for (int c0 = wave * 4; c0 < cnt; c0 += 64) {
        const int cA = c0, cB = c0 + 1, cC = c0 + 2, cD = c0 + 3;
        const bool hB = cB < cnt, hC = cC < cnt, hD = cD < cnt;
        const int nA = candLds[cA];
        const int nB = hB ? candLds[cB] : nA;
        const int nC = hC ? candLds[cC] : nA;
        const int nD = hD ? candLds[cD] : nA;
        const float* xrA = x1 + (size_t)nA * DIMN;
        const float* xrB = x1 + (size_t)nB * DIMN;
        const float* xrC = x1 + (size_t)nC * DIMN;
        const float* xrD = x1 + (size_t)nD * DIMN;

        double aA = 0.0, aB = 0.0, aC = 0.0, aD = 0.0;
        #pragma unroll
        for (int j = 0; j < 4; ++j) {
            float4 xa = *(const float4*)(xrA + lane * 4 + j * 256);
            float4 xb = *(const float4*)(xrB + lane * 4 + j * 256);
            float4 xc = *(const float4*)(xrC + lane * 4 + j * 256);
            float4 xd = *(const float4*)(xrD + lane * 4 + j * 256);
            aA += (double)xa.x * wr[j * 4 + 0] + (double)xa.y * wr[j * 4 + 1] +
                  (double)xa.z * wr[j * 4 + 2] + (double)xa.w * wr[j * 4 + 3];
            aB += (double)xb.x * wr[j * 4 + 0] + (double)xb.y * wr[j * 4 + 1] +
                  (double)xb.z * wr[j * 4 + 2] + (double)xb.w * wr[j * 4 + 3];
            aC += (double)xc.x * wr[j * 4 + 0] + (double)xc.y * wr[j * 4 + 1] +
                  (double)xc.z * wr[j * 4 + 2] + (double)xc.w * wr[j * 4 + 3];
            aD += (double)xd.x * wr[j * 4 + 0] + (double)xd.y * wr[j * 4 + 1] +
                  (double)xd.z * wr[j * 4 + 2] + (double)xd.w * wr[j * 4 + 3];
        }
        aA = wave_reduce_sum_d(aA);
        aB = wave_reduce_sum_d(aB);
        aC = wave_reduce_sum_d(aC);
        aD = wave_reduce_sum_d(aD);
        if (lane == 0) {
            {
                const double mu1 = stats1[(size_t)nA * 3 + 0];
                const double rstd1 = stats1[(size_t)nA * 3 + 1];
                const double invn1 = stats1[(size_t)nA * 3 + 2];
                valsLds[cA] = (rstd1 * invn1) * (aA - mu1 * C2) + invn1 * C1;
            }
            if (hB) {
                const double mu1 = stats1[(size_t)nB * 3 + 0];
                const double rstd1 = stats1[(size_t)nB * 3 + 1];
                const double invn1 = stats1[(size_t)nB * 3 + 2];
                valsLds[cB] = (rstd1 * invn1) * (aB - mu1 * C2) + invn1 * C1;
            }
            if (hC) {
                const double mu1 = stats1[(size_t)nC * 3 + 0];
                const double rstd1 = stats1[(size_t)nC * 3 + 1];
                const double invn1 = stats1[(size_t)nC * 3 + 2];
                valsLds[cC] = (rstd1 * invn1) * (aC - mu1 * C2) + invn1 * C1;
            }
            if (hD) {
                const double mu1 = stats1[(size_t)nD * 3 + 0];
                const double rstd1 = stats1[(size_t)nD * 3 + 1];
                const double invn1 = stats1[(size_t)nD * 3 + 2];
                valsLds[cD] = (rstd1 * invn1) * (aD - mu1 * C2) + invn1 * C1;
            }
        }
    }
    __syncthreads();

    // --- E: wave 0 exact top-64 tournament ---
    if (wave == 0) {
        double v0 = valsLds[lane],       v1 = valsLds[lane + 64];
        double v2 = valsLds[lane + 128], v3 = valsLds[lane + 192];
        int i0 = candLds[lane],       i1 = candLds[lane + 64];
        int i2 = candLds[lane + 128], i3 = candLds[lane + 192];

        for (int k = 0; k < KTOP; ++k) {
            bool a01 = (v0 > v1) || (v0 == v1 && i0 < i1);
            double va = a01 ? v0 : v1; int ia = a01 ? i0 : i1; int sa = a01 ? 0 : 1;
            bool a23 = (v2 > v3) || (v2 == v3 && i2 < i3);
            double vb = a23 ? v2 : v3; int ib = a23 ? i2 : i3; int sb = a23 ? 2 : 3;
            bool ab = (va > vb) || (va == vb && ia < ib);
            double mv = ab ? va : vb; int mi = ab ? ia : ib; int slot = ab ? sa : sb;
            int owner = lane;
            #pragma unroll
            for (int off = 32; off > 0; off >>= 1) {
                double ov = __shfl_down(mv, off, 64);
                int oi = __shfl_down(mi, off, 64);
                int oo = __shfl_down(owner, off, 64);
                int os = __shfl_down(slot, off, 64);
                bool take = (ov > mv) || (ov == mv && oi < mi);
                if (take) { mv = ov; mi = oi; owner = oo; slot = os; }
            }
            int wown = __shfl(owner, 0, 64);
            int wslot = __shfl(slot, 0, 64);
            int wmi = __shfl(mi, 0, 64);
            if (lane == 0) out[(size_t)q * KTOP + k] = (float)wmi * (1.0f / 32768.0f);
            if (lane == wown) {
                v0 = (wslot == 0) ? -1e300 : v0;
                v1 = (wslot == 1) ? -1e300 : v1;
                v2 = (wslot == 2) ? -1e300 : v2;
                v3 = (wslot == 3) ? -1e300 : v3;
            }
        }
    }
}

// ---------------------------------------------------------------------------
extern "C" void kernel_launch(void* const* d_in, const int* in_sizes, int n_in,
                              void* d_out, int out_size, void* d_ws, size_t ws_size,
                              hipStream_t stream) {
    const float* prior = (const float*)d_in[0];
    const float* clip  = (const float*)d_in[1];
    const float* g1    = (const float*)d_in[2];
    const float* b1    = (const float*)d_in[3];
    const float* g2    = (const float*)d_in[4];
    const float* b2    = (const float*)d_in[5];
    float* out = (float*)d_out;

    char* ws = (char*)d_ws;
    size_t off = 0;
    double* stats1 = (double*)(ws + off); off += (size_t)N1C * 3 * sizeof(double);
    __hip_bfloat16* x1n = (__hip_bfloat16*)(ws + off); off += (size_t)N1C * DIMN * 2;
    __hip_bfloat16* x2n = (__hip_bfloat16*)(ws + off); off += (size_t)N2C * DIMN * 2;
    ushort_t* simkey = (ushort_t*)(ws + off); off += (size_t)N2C * N1C * 2;
    unsigned* segcand = (unsigned*)(ws + off); off += (size_t)N2C * 4 * SEGCAP * 4;
    int* segcnt = (int*)(ws + off); off += (size_t)N2C * 4 * sizeof(int);
    double* wq = (double*)(ws + off); off += (size_t)N2C * DIMN * sizeof(double);
    double* consts = (double*)(ws + off); off += (size_t)N2C * 2 * sizeof(double);

    ln_all<<<N1C / 4 + N2C / 4, 256, 0, stream>>>(
        prior, clip, g1, b1, g2, b2, x1n, x2n, stats1, wq, consts);

    sim_gemm<<<(N1C / BN) * (N2C / BM), 256, 0, stream>>>(x2n, x1n, simkey);

    seg_topk_reg<<<N2C * 4, 256, 0, stream>>>(simkey, segcand, segcnt);

    merge_score_select<<<N2C, 1024, 0, stream>>>(
        segcand, segcnt, prior, stats1, wq, consts, out);
}

// Round 13
// 209.922 us; speedup vs baseline: 1.2765x; 1.2765x over previous
//
#include <hip/hip_runtime.h>
#include <hip/hip_bf16.h>
#include <stdint.h>

#define DIMN 1024
#define N1C 32768
#define N2C 512
#define KTOP 64
#define MCAND 80
#define CAP 256
#define SEG 8192
#define SEGCAP 256

typedef unsigned short ushort_t;
typedef __attribute__((ext_vector_type(8))) short short8;
typedef __attribute__((ext_vector_type(4))) float f32x4;

__device__ __forceinline__ double wave_reduce_sum_d(double v) {
    #pragma unroll
    for (int off = 32; off > 0; off >>= 1)
        v += __shfl_down(v, off, 64);
    return v;
}

__device__ __forceinline__ unsigned wave_reduce_sum_u(unsigned v) {
    #pragma unroll
    for (int off = 32; off > 0; off >>= 1)
        v += __shfl_down(v, off, 64);
    return v;
}

__device__ __forceinline__ void gload_lds16(const void* g, void* l) {
    __builtin_amdgcn_global_load_lds(
        (const __attribute__((address_space(1))) unsigned*)g,
        (__attribute__((address_space(3))) unsigned*)l, 16, 0, 0);
}

__device__ __forceinline__ ushort_t f2bf(float f) {
    __hip_bfloat16 h = __float2bfloat16(f);
    return *reinterpret_cast<ushort_t*>(&h);
}

__device__ __forceinline__ unsigned key_of_bf16(unsigned u16) {
    return (u16 & 0x8000u) ? (0xFFFFu & ~u16) : (u16 | 0x8000u);
}

// ---------------------------------------------------------------------------
// Kernel 1: fused LN for BOTH inputs, wave-per-row, barrier-free.
// ---------------------------------------------------------------------------
__global__ __launch_bounds__(256) void ln_all(
    const float* __restrict__ prior, const float* __restrict__ clip,
    const float* __restrict__ g1, const float* __restrict__ b1,
    const float* __restrict__ g2, const float* __restrict__ b2,
    __hip_bfloat16* __restrict__ x1n, __hip_bfloat16* __restrict__ x2n,
    double* __restrict__ stats1, double* __restrict__ wq,
    double* __restrict__ consts) {
    const int bid = blockIdx.x;
    const int tid = threadIdx.x;
    const int lane = tid & 63, wave = tid >> 6;

    if (bid < N1C / 4) {
        const int row = bid * 4 + wave;
        const float* xr = prior + (size_t)row * DIMN;
        float4 xv[4], gv[4], bv[4];
        #pragma unroll
        for (int j = 0; j < 4; ++j) {
            xv[j] = *(const float4*)(xr + lane * 4 + j * 256);
            gv[j] = *(const float4*)(g1 + lane * 4 + j * 256);
            bv[j] = *(const float4*)(b1 + lane * 4 + j * 256);
        }
        double s = 0.0, s2 = 0.0;
        #pragma unroll
        for (int j = 0; j < 4; ++j) {
            double a = xv[j].x, b = xv[j].y, c = xv[j].z, d = xv[j].w;
            s += (a + b) + (c + d);
            s2 += (a * a + b * b) + (c * c + d * d);
        }
        s = wave_reduce_sum_d(s);
        s2 = wave_reduce_sum_d(s2);
        double mu, rstd;
        if (lane == 0) {
            mu = s / (double)DIMN;
            double var = s2 / (double)DIMN - mu * mu;
            rstd = 1.0 / sqrt(var + 1e-5);
        }
        mu = __shfl(mu, 0, 64);
        rstd = __shfl(rstd, 0, 64);

        double y[16];
        double q = 0.0;
        #pragma unroll
        for (int j = 0; j < 4; ++j) {
            double y0 = ((double)xv[j].x - mu) * rstd * (double)gv[j].x + (double)bv[j].x;
            double y1 = ((double)xv[j].y - mu) * rstd * (double)gv[j].y + (double)bv[j].y;
            double y2 = ((double)xv[j].z - mu) * rstd * (double)gv[j].z + (double)bv[j].z;
            double y3 = ((double)xv[j].w - mu) * rstd * (double)gv[j].w + (double)bv[j].w;
            y[j * 4 + 0] = y0; y[j * 4 + 1] = y1; y[j * 4 + 2] = y2; y[j * 4 + 3] = y3;
            q += (y0 * y0 + y1 * y1) + (y2 * y2 + y3 * y3);
        }
        q = wave_reduce_sum_d(q);
        double invn;
        if (lane == 0) {
            invn = 1.0 / fmax(sqrt(q), 1e-8);
            stats1[(size_t)row * 3 + 0] = mu;
            stats1[(size_t)row * 3 + 1] = rstd;
            stats1[(size_t)row * 3 + 2] = invn;
        }
        invn = __shfl(invn, 0, 64);

        ushort_t* dst = (ushort_t*)x1n + (size_t)row * DIMN;
        #pragma unroll
        for (int j = 0; j < 4; ++j) {
            uint2 pk;
            pk.x = (unsigned)f2bf((float)(y[j * 4 + 0] * invn)) |
                   ((unsigned)f2bf((float)(y[j * 4 + 1] * invn)) << 16);
            pk.y = (unsigned)f2bf((float)(y[j * 4 + 2] * invn)) |
                   ((unsigned)f2bf((float)(y[j * 4 + 3] * invn)) << 16);
            *(uint2*)(dst + lane * 4 + j * 256) = pk;
        }
    } else {
        const int q = (bid - N1C / 4) * 4 + wave;
        const float* xr = clip + (size_t)q * DIMN;
        float4 xv[4];
        #pragma unroll
        for (int j = 0; j < 4; ++j)
            xv[j] = *(const float4*)(xr + lane * 4 + j * 256);

        double s = 0.0, s2 = 0.0;
        #pragma unroll
        for (int j = 0; j < 4; ++j) {
            double a = xv[j].x, b = xv[j].y, c = xv[j].z, d = xv[j].w;
            s += (a + b) + (c + d);
            s2 += (a * a + b * b) + (c * c + d * d);
        }
        s = wave_reduce_sum_d(s);
        s2 = wave_reduce_sum_d(s2);
        double mu, rstd;
        if (lane == 0) {
            mu = s / (double)DIMN;
            double var = s2 / (double)DIMN - mu * mu;
            rstd = 1.0 / sqrt(var + 1e-5);
        }
        mu = __shfl(mu, 0, 64);
        rstd = __shfl(rstd, 0, 64);

        double yv[16];
        double qq = 0.0;
        #pragma unroll
        for (int j = 0; j < 4; ++j) {
            const float4 g2v = *(const float4*)(g2 + lane * 4 + j * 256);
            const float4 b2v = *(const float4*)(b2 + lane * 4 + j * 256);
            double y0 = ((double)xv[j].x - mu) * rstd * (double)g2v.x + (double)b2v.x;
            double y1 = ((double)xv[j].y - mu) * rstd * (double)g2v.y + (double)b2v.y;
            double y2 = ((double)xv[j].z - mu) * rstd * (double)g2v.z + (double)b2v.z;
            double y3 = ((double)xv[j].w - mu) * rstd * (double)g2v.w + (double)b2v.w;
            yv[j * 4 + 0] = y0; yv[j * 4 + 1] = y1;
            yv[j * 4 + 2] = y2; yv[j * 4 + 3] = y3;
            qq += (y0 * y0 + y1 * y1) + (y2 * y2 + y3 * y3);
        }
        qq = wave_reduce_sum_d(qq);
        double invn;
        if (lane == 0) invn = 1.0 / fmax(sqrt(qq), 1e-8);
        invn = __shfl(invn, 0, 64);

        double c1 = 0.0, c2 = 0.0;
        ushort_t* dst = (ushort_t*)x2n + (size_t)q * DIMN;
        double* wrow = wq + (size_t)q * DIMN;
        #pragma unroll
        for (int j = 0; j < 4; ++j) {
            double y0 = yv[j * 4 + 0] * invn, y1 = yv[j * 4 + 1] * invn;
            double y2 = yv[j * 4 + 2] * invn, y3 = yv[j * 4 + 3] * invn;
            uint2 pk;
            pk.x = (unsigned)f2bf((float)y0) | ((unsigned)f2bf((float)y1) << 16);
            pk.y = (unsigned)f2bf((float)y2) | ((unsigned)f2bf((float)y3) << 16);
            *(uint2*)(dst + lane * 4 + j * 256) = pk;

            const float4 g1v = *(const float4*)(g1 + lane * 4 + j * 256);
            const float4 b1v = *(const float4*)(b1 + lane * 4 + j * 256);
            double w0 = y0 * (double)g1v.x, w1 = y1 * (double)g1v.y;
            double w2 = y2 * (double)g1v.z, w3 = y3 * (double)g1v.w;
            double* wp = wrow + lane * 4 + j * 256;
            double2 t0; t0.x = w0; t0.y = w1;
            double2 t1; t1.x = w2; t1.y = w3;
            *(double2*)(wp) = t0;
            *(double2*)(wp + 2) = t1;
            c1 += ((double)b1v.x * y0 + (double)b1v.y * y1) +
                  ((double)b1v.z * y2 + (double)b1v.w * y3);
            c2 += (w0 + w1) + (w2 + w3);
        }
        c1 = wave_reduce_sum_d(c1);
        c2 = wave_reduce_sum_d(c2);
        if (lane == 0) {
            consts[(size_t)q * 2 + 0] = c1;
            consts[(size_t)q * 2 + 1] = c2;
        }
    }
}

// ---------------------------------------------------------------------------
// Kernel 2: candidate GEMM via MFMA (m97 structure, BK=64, XCD swizzle).
// Epilogue: stage key tile in LDS (padded stride 136), then coalesced
// dwordx4 global stores (replaces 64 scalar ushort stores/thread).
// ---------------------------------------------------------------------------
#define BM 128
#define BN 128
#define BKG 64
#define CPAD 136

__global__ __launch_bounds__(256) void sim_gemm(
    const __hip_bfloat16* __restrict__ x2n, const __hip_bfloat16* __restrict__ x1n,
    ushort_t* __restrict__ simkey) {
    // 34816 B: holds As(16KB)+Bs(16KB) during K-loop, C-tile (128x136) after.
    __shared__ __align__(16) ushort_t smem[BM * CPAD];
    ushort_t (*As)[BKG] = (ushort_t(*)[BKG])smem;
    ushort_t (*Bs)[BKG] = (ushort_t(*)[BKG])(smem + BM * BKG);

    const int bid = blockIdx.x;
    const int l = (bid & 7) * 128 + (bid >> 3);
    const int q0 = (l & 3) * BM;
    const int n0 = (l >> 2) * BN;

    const int tid = threadIdx.x;
    const int ln = tid & 63, wv = tid >> 6;
    const int wr = wv >> 1, wc = wv & 1;

    const int st_r = ln >> 3;
    const int st_c = (ln & 7) * 8;

    const ushort_t* Ab = (const ushort_t*)x2n;
    const ushort_t* Bb = (const ushort_t*)x1n;

    f32x4 acc[4][4];
    #pragma unroll
    for (int m = 0; m < 4; ++m)
        #pragma unroll
        for (int n = 0; n < 4; ++n) acc[m][n] = (f32x4)0.0f;

    const int lr = ln & 15;
    const int lk = (ln >> 4) * 8;

    for (int kt = 0; kt < DIMN; kt += BKG) {
        #pragma unroll
        for (int i = 0; i < 4; ++i) {
            int ci = i * 4 + wv;
            int row = ci * 8 + st_r;
            gload_lds16(Ab + (size_t)(q0 + row) * DIMN + kt + st_c,
                        (char*)&As[0][0] + ci * 1024);
            gload_lds16(Bb + (size_t)(n0 + row) * DIMN + kt + st_c,
                        (char*)&Bs[0][0] + ci * 1024);
        }
        __syncthreads();

        short8 af[4][2], bfr[4][2];
        #pragma unroll
        for (int m = 0; m < 4; ++m) {
            af[m][0] = *(const short8*)&As[wr * 64 + m * 16 + lr][lk];
            af[m][1] = *(const short8*)&As[wr * 64 + m * 16 + lr][32 + lk];
        }
        #pragma unroll
        for (int n = 0; n < 4; ++n) {
            bfr[n][0] = *(const short8*)&Bs[wc * 64 + n * 16 + lr][lk];
            bfr[n][1] = *(const short8*)&Bs[wc * 64 + n * 16 + lr][32 + lk];
        }
        #pragma unroll
        for (int m = 0; m < 4; ++m)
            #pragma unroll
            for (int n = 0; n < 4; ++n) {
                acc[m][n] = __builtin_amdgcn_mfma_f32_16x16x32_bf16(
                    af[m][0], bfr[n][0], acc[m][n], 0, 0, 0);
                acc[m][n] = __builtin_amdgcn_mfma_f32_16x16x32_bf16(
                    af[m][1], bfr[n][1], acc[m][n], 0, 0, 0);
            }
        __syncthreads();
    }

    // epilogue: stage keys in LDS, then coalesced stores
    const int crow = (ln >> 4) * 4;
    #pragma unroll
    for (int m = 0; m < 4; ++m) {
        #pragma unroll
        for (int n = 0; n < 4; ++n) {
            int col_l = wc * 64 + n * 16 + lr;
            #pragma unroll
            for (int r = 0; r < 4; ++r) {
                int row_l = wr * 64 + m * 16 + crow + r;
                smem[row_l * CPAD + col_l] =
                    (ushort_t)key_of_bf16((unsigned)f2bf(acc[m][n][r]));
            }
        }
    }
    __syncthreads();
    #pragma unroll
    for (int i = 0; i < 8; ++i) {
        int idx = i * 256 + tid;          // uint4 index; 16 per row
        int row = idx >> 4, c16 = idx & 15;
        uint4 v = *(const uint4*)(smem + row * CPAD + c16 * 8);
        *(uint4*)(simkey + (size_t)(q0 + row) * N1C + n0 + c16 * 8) = v;
    }
}

// ---------------------------------------------------------------------------
// Kernel 3: per-(q, segment) top->=MCAND. Grid 2048 blocks, keys in
// REGISTERS, 16 bisection passes with one LDS-atomic count + barrier each.
// ---------------------------------------------------------------------------
__global__ __launch_bounds__(256) void seg_topk_reg(
    const ushort_t* __restrict__ simkey, unsigned* __restrict__ segcand,
    int* __restrict__ segcnt) {
    const int bid = blockIdx.x;
    const int seg = bid & 3, q = bid >> 2;
    const int tid = threadIdx.x;
    const int lane = tid & 63;

    __shared__ unsigned csum[16];
    __shared__ unsigned scnt;

    if (tid < 16) csum[tid] = 0;
    if (tid == 0) scnt = 0;
    __syncthreads();

    const unsigned* rowPair =
        (const unsigned*)(simkey + (size_t)q * N1C) + seg * (SEG / 2);
    unsigned kreg[16];
    #pragma unroll
    for (int s = 0; s < 16; ++s)
        kreg[s] = rowPair[s * 256 + tid];

    unsigned lo = 0, hi = 65536;
    #pragma unroll 1
    for (int pass = 0; pass < 16; ++pass) {
        unsigned mid = (lo + hi) >> 1;
        unsigned c = 0;
        #pragma unroll
        for (int s = 0; s < 16; ++s) {
            c += ((kreg[s] & 0xFFFFu) >= mid) ? 1u : 0u;
            c += ((kreg[s] >> 16)     >= mid) ? 1u : 0u;
        }
        c = wave_reduce_sum_u(c);
        if (lane == 0) atomicAdd(&csum[pass], c);
        __syncthreads();
        if (csum[pass] >= MCAND) lo = mid; else hi = mid;
    }
    const unsigned thr_w = lo;

    #pragma unroll
    for (int s = 0; s < 16; ++s) {
        unsigned k0 = kreg[s] & 0xFFFFu, k1 = kreg[s] >> 16;
        unsigned e0 = (unsigned)(seg * SEG + (s * 256 + tid) * 2);
        if (k0 >= thr_w) {
            unsigned p = atomicAdd(&scnt, 1u);
            if (p < SEGCAP) segcand[(size_t)bid * SEGCAP + p] = (k0 << 16) | e0;
        }
        if (k1 >= thr_w) {
            unsigned p = atomicAdd(&scnt, 1u);
            if (p < SEGCAP) segcand[(size_t)bid * SEGCAP + p] = (k1 << 16) | (e0 + 1);
        }
    }
    __syncthreads();
    if (tid == 0) segcnt[bid] = (int)(scnt < SEGCAP ? scnt : SEGCAP);
}

// ---------------------------------------------------------------------------
// Kernel 3b: merge 4 segments' candidates, global threshold, emit cand list.
// ---------------------------------------------------------------------------
__global__ __launch_bounds__(256) void merge_cand(
    const unsigned* __restrict__ segcand, const int* __restrict__ segcnt,
    int* __restrict__ cand, int* __restrict__ cand_cnt) {
    const int q = blockIdx.x;
    const int tid = threadIdx.x;
    const int lane = tid & 63, wave = tid >> 6;

    __shared__ unsigned buf[4 * SEGCAP];
    __shared__ int offs[5];
    __shared__ unsigned wred[4];
    __shared__ unsigned bc;
    __shared__ unsigned cnt;

    if (tid == 0) {
        int o = 0;
        #pragma unroll
        for (int s = 0; s < 4; ++s) { offs[s] = o; o += segcnt[q * 4 + s]; }
        offs[4] = o;
        cnt = 0;
    }
    __syncthreads();
    const int tot = offs[4];
    #pragma unroll
    for (int s = 0; s < 4; ++s) {
        int cs = offs[s + 1] - offs[s];
        for (int i = tid; i < cs; i += 256)
            buf[offs[s] + i] = segcand[(size_t)(q * 4 + s) * SEGCAP + i];
    }
    __syncthreads();

    unsigned lo = 0, hi = 65536;
    for (int pass = 0; pass < 16; ++pass) {
        unsigned mid = (lo + hi) >> 1;
        unsigned c = 0;
        for (int i = tid; i < tot; i += 256)
            c += ((buf[i] >> 16) >= mid) ? 1u : 0u;
        c = wave_reduce_sum_u(c);
        if (lane == 0) wred[wave] = c;
        __syncthreads();
        if (tid == 0) bc = wred[0] + wred[1] + wred[2] + wred[3];
        __syncthreads();
        if (bc >= MCAND) lo = mid; else hi = mid;
    }
    const unsigned thr = lo;

    for (int i = tid; i < tot; i += 256) {
        unsigned b = buf[i];
        if ((b >> 16) >= thr) {
            unsigned p = atomicAdd(&cnt, 1u);
            if (p < CAP) cand[(size_t)q * CAP + p] = (int)(b & 0xFFFFu);
        }
    }
    __syncthreads();
    if (tid == 0) cand_cnt[q] = (int)(cnt < CAP ? cnt : CAP);
}

// ---------------------------------------------------------------------------
// Kernel 4a: fp64 factorized scoring, 4 candidates in flight per wave.
// grid (q, 16 chunks of 16 cands).
// ---------------------------------------------------------------------------
__global__ __launch_bounds__(256) void score_cand(
    const float* __restrict__ x1, const double* __restrict__ stats1,
    const double* __restrict__ wq, const double* __restrict__ consts,
    const int* __restrict__ cand, const int* __restrict__ cand_cnt,
    double* __restrict__ vals) {
    const int q = blockIdx.x, chunk = blockIdx.y;
    const int tid = threadIdx.x;
    const int lane = tid & 63, wv = tid >> 6;
    const int cnt = cand_cnt[q];
    const int cbase = chunk * 16;
    if (cbase >= cnt) return;

    const double C1 = consts[(size_t)q * 2 + 0];
    const double C2 = consts[(size_t)q * 2 + 1];

    const double* w = wq + (size_t)q * DIMN;
    double wr[16];
    #pragma unroll
    for (int j = 0; j < 4; ++j) {
        double2 a = *(const double2*)(w + lane * 4 + j * 256);
        double2 b = *(const double2*)(w + lane * 4 + j * 256 + 2);
        wr[j * 4 + 0] = a.x; wr[j * 4 + 1] = a.y;
        wr[j * 4 + 2] = b.x; wr[j * 4 + 3] = b.y;
    }

    const int cA = cbase + wv;
    const int cB = cA + 4;
    const int cC = cA + 8;
    const int cD = cA + 12;
    const bool hA = cA < cnt, hB = cB < cnt, hC = cC < cnt, hD = cD < cnt;
    if (!hA) return;
    const int nA = cand[(size_t)q * CAP + cA];
    const int nB = hB ? cand[(size_t)q * CAP + cB] : nA;
    const int nC = hC ? cand[(size_t)q * CAP + cC] : nA;
    const int nD = hD ? cand[(size_t)q * CAP + cD] : nA;
    const float* xrA = x1 + (size_t)nA * DIMN;
    const float* xrB = x1 + (size_t)nB * DIMN;
    const float* xrC = x1 + (size_t)nC * DIMN;
    const float* xrD = x1 + (size_t)nD * DIMN;

    double aA = 0.0, aB = 0.0, aC = 0.0, aD = 0.0;
    #pragma unroll
    for (int j = 0; j < 4; ++j) {
        float4 xa = *(const float4*)(xrA + lane * 4 + j * 256);
        float4 xb = *(const float4*)(xrB + lane * 4 + j * 256);
        float4 xc = *(const float4*)(xrC + lane * 4 + j * 256);
        float4 xd = *(const float4*)(xrD + lane * 4 + j * 256);
        aA += (double)xa.x * wr[j * 4 + 0] + (double)xa.y * wr[j * 4 + 1] +
              (double)xa.z * wr[j * 4 + 2] + (double)xa.w * wr[j * 4 + 3];
        aB += (double)xb.x * wr[j * 4 + 0] + (double)xb.y * wr[j * 4 + 1] +
              (double)xb.z * wr[j * 4 + 2] + (double)xb.w * wr[j * 4 + 3];
        aC += (double)xc.x * wr[j * 4 + 0] + (double)xc.y * wr[j * 4 + 1] +
              (double)xc.z * wr[j * 4 + 2] + (double)xc.w * wr[j * 4 + 3];
        aD += (double)xd.x * wr[j * 4 + 0] + (double)xd.y * wr[j * 4 + 1] +
              (double)xd.z * wr[j * 4 + 2] + (double)xd.w * wr[j * 4 + 3];
    }
    aA = wave_reduce_sum_d(aA);
    aB = wave_reduce_sum_d(aB);
    aC = wave_reduce_sum_d(aC);
    aD = wave_reduce_sum_d(aD);
    if (lane == 0) {
        {
            const double mu1 = stats1[(size_t)nA * 3 + 0];
            const double rstd1 = stats1[(size_t)nA * 3 + 1];
            const double invn1 = stats1[(size_t)nA * 3 + 2];
            vals[(size_t)q * CAP + cA] = (rstd1 * invn1) * (aA - mu1 * C2) + invn1 * C1;
        }
        if (hB) {
            const double mu1 = stats1[(size_t)nB * 3 + 0];
            const double rstd1 = stats1[(size_t)nB * 3 + 1];
            const double invn1 = stats1[(size_t)nB * 3 + 2];
            vals[(size_t)q * CAP + cB] = (rstd1 * invn1) * (aB - mu1 * C2) + invn1 * C1;
        }
        if (hC) {
            const double mu1 = stats1[(size_t)nC * 3 + 0];
            const double rstd1 = stats1[(size_t)nC * 3 + 1];
            const double invn1 = stats1[(size_t)nC * 3 + 2];
            vals[(size_t)q * CAP + cC] = (rstd1 * invn1) * (aC - mu1 * C2) + invn1 * C1;
        }
        if (hD) {
            const double mu1 = stats1[(size_t)nD * 3 + 0];
            const double rstd1 = stats1[(size_t)nD * 3 + 1];
            const double invn1 = stats1[(size_t)nD * 3 + 2];
            vals[(size_t)q * CAP + cD] = (rstd1 * invn1) * (aD - mu1 * C2) + invn1 * C1;
        }
    }
}

// ---------------------------------------------------------------------------
// Kernel 4b: exact top-64 selection (value desc, idx asc). One wave per q.
// ---------------------------------------------------------------------------
__global__ __launch_bounds__(64) void select_topk(
    const double* __restrict__ vals, const int* __restrict__ cand,
    const int* __restrict__ cand_cnt, float* __restrict__ out) {
    const int q = blockIdx.x;
    const int lane = threadIdx.x;
    const int cnt = cand_cnt[q];

    double v0 = (lane < cnt)       ? vals[(size_t)q * CAP + lane]       : -1e300;
    double v1 = (lane + 64 < cnt)  ? vals[(size_t)q * CAP + lane + 64]  : -1e300;
    double v2 = (lane + 128 < cnt) ? vals[(size_t)q * CAP + lane + 128] : -1e300;
    double v3 = (lane + 192 < cnt) ? vals[(size_t)q * CAP + lane + 192] : -1e300;
    int i0 = (lane < cnt)       ? cand[(size_t)q * CAP + lane]       : 0x7FFFFFFF;
    int i1 = (lane + 64 < cnt)  ? cand[(size_t)q * CAP + lane + 64]  : 0x7FFFFFFF;
    int i2 = (lane + 128 < cnt) ? cand[(size_t)q * CAP + lane + 128] : 0x7FFFFFFF;
    int i3 = (lane + 192 < cnt) ? cand[(size_t)q * CAP + lane + 192] : 0x7FFFFFFF;

    for (int k = 0; k < KTOP; ++k) {
        bool a01 = (v0 > v1) || (v0 == v1 && i0 < i1);
        double va = a01 ? v0 : v1; int ia = a01 ? i0 : i1; int sa = a01 ? 0 : 1;
        bool a23 = (v2 > v3) || (v2 == v3 && i2 < i3);
        double vb = a23 ? v2 : v3; int ib = a23 ? i2 : i3; int sb = a23 ? 2 : 3;
        bool ab = (va > vb) || (va == vb && ia < ib);
        double mv = ab ? va : vb; int mi = ab ? ia : ib; int slot = ab ? sa : sb;
        int owner = lane;
        #pragma unroll
        for (int off = 32; off > 0; off >>= 1) {
            double ov = __shfl_down(mv, off, 64);
            int oi = __shfl_down(mi, off, 64);
            int oo = __shfl_down(owner, off, 64);
            int os = __shfl_down(slot, off, 64);
            bool take = (ov > mv) || (ov == mv && oi < mi);
            if (take) { mv = ov; mi = oi; owner = oo; slot = os; }
        }
        int wown = __shfl(owner, 0, 64);
        int wslot = __shfl(slot, 0, 64);
        int wmi = __shfl(mi, 0, 64);
        if (lane == 0) out[(size_t)q * KTOP + k] = (float)wmi * (1.0f / 32768.0f);
        if (lane == wown) {
            v0 = (wslot == 0) ? -1e300 : v0;
            v1 = (wslot == 1) ? -1e300 : v1;
            v2 = (wslot == 2) ? -1e300 : v2;
            v3 = (wslot == 3) ? -1e300 : v3;
        }
    }
}

// ---------------------------------------------------------------------------
extern "C" void kernel_launch(void* const* d_in, const int* in_sizes, int n_in,
                              void* d_out, int out_size, void* d_ws, size_t ws_size,
                              hipStream_t stream) {
    const float* prior = (const float*)d_in[0];
    const float* clip  = (const float*)d_in[1];
    const float* g1    = (const float*)d_in[2];
    const float* b1    = (const float*)d_in[3];
    const float* g2    = (const float*)d_in[4];
    const float* b2    = (const float*)d_in[5];
    float* out = (float*)d_out;

    char* ws = (char*)d_ws;
    size_t off = 0;
    double* stats1 = (double*)(ws + off); off += (size_t)N1C * 3 * sizeof(double);
    __hip_bfloat16* x1n = (__hip_bfloat16*)(ws + off); off += (size_t)N1C * DIMN * 2;
    __hip_bfloat16* x2n = (__hip_bfloat16*)(ws + off); off += (size_t)N2C * DIMN * 2;
    ushort_t* simkey = (ushort_t*)(ws + off); off += (size_t)N2C * N1C * 2;
    unsigned* segcand = (unsigned*)(ws + off); off += (size_t)N2C * 4 * SEGCAP * 4;
    int* segcnt = (int*)(ws + off); off += (size_t)N2C * 4 * sizeof(int);
    int* cand = (int*)(ws + off); off += (size_t)N2C * CAP * sizeof(int);
    int* cand_cnt = (int*)(ws + off); off += (size_t)N2C * sizeof(int);
    double* wq = (double*)(ws + off); off += (size_t)N2C * DIMN * sizeof(double);
    double* consts = (double*)(ws + off); off += (size_t)N2C * 2 * sizeof(double);
    double* vals = (double*)(ws + off); off += (size_t)N2C * CAP * sizeof(double);

    ln_all<<<N1C / 4 + N2C / 4, 256, 0, stream>>>(
        prior, clip, g1, b1, g2, b2, x1n, x2n, stats1, wq, consts);

    sim_gemm<<<(N1C / BN) * (N2C / BM), 256, 0, stream>>>(x2n, x1n, simkey);

    seg_topk_reg<<<N2C * 4, 256, 0, stream>>>(simkey, segcand, segcnt);
    merge_cand<<<N2C, 256, 0, stream>>>(segcand, segcnt, cand, cand_cnt);

    dim3 gs(N2C, 16);
    score_cand<<<gs, 256, 0, stream>>>(prior, stats1, wq, consts, cand, cand_cnt, vals);
    select_topk<<<N2C, 64, 0, stream>>>(vals, cand, cand_cnt, out);
}

// Round 14
// 199.437 us; speedup vs baseline: 1.3436x; 1.0526x over previous
//
#include <hip/hip_runtime.h>
#include <hip/hip_bf16.h>
#include <stdint.h>

#define DIMN 1024
#define N1C 32768
#define N2C 512
#define KTOP 64
#define MCAND 80
#define CAP 256
#define SEG 8192
#define SEGCAP 256

typedef unsigned short ushort_t;
typedef __attribute__((ext_vector_type(8))) short short8;
typedef __attribute__((ext_vector_type(4))) float f32x4;

__device__ __forceinline__ double wave_reduce_sum_d(double v) {
    #pragma unroll
    for (int off = 32; off > 0; off >>= 1)
        v += __shfl_down(v, off, 64);
    return v;
}

__device__ __forceinline__ void gload_lds16(const void* g, void* l) {
    __builtin_amdgcn_global_load_lds(
        (const __attribute__((address_space(1))) unsigned*)g,
        (__attribute__((address_space(3))) unsigned*)l, 16, 0, 0);
}

__device__ __forceinline__ ushort_t f2bf(float f) {
    __hip_bfloat16 h = __float2bfloat16(f);
    return *reinterpret_cast<ushort_t*>(&h);
}

__device__ __forceinline__ unsigned key_of_bf16(unsigned u16) {
    return (u16 & 0x8000u) ? (0xFFFFu & ~u16) : (u16 | 0x8000u);
}

// Wave-0 radix scan over a 256-bin LDS histogram: finds largest byte b with
// suffix-count S(b) >= need (S non-increasing). Writes b and S(b+1) (count
// strictly above the bin) to LDS. Exactly one lane's condition fires.
__device__ __forceinline__ void radix_scan_w0(
    const unsigned* hist, unsigned need, int lane,
    unsigned* out_b, unsigned* out_above) {
    unsigned p0 = hist[lane * 4 + 0], p1 = hist[lane * 4 + 1];
    unsigned p2 = hist[lane * 4 + 2], p3 = hist[lane * 4 + 3];
    unsigned suf = p0 + p1 + p2 + p3;
    #pragma unroll
    for (int off = 1; off < 64; off <<= 1) {
        unsigned o = __shfl_down(suf, off, 64);
        if (lane + off < 64) suf += o;
    }
    unsigned next = __shfl_down(suf, 1, 64);
    if (lane == 63) next = 0u;
    unsigned s3 = next + p3;
    unsigned s2 = s3 + p2;
    unsigned s1 = s2 + p1;
    unsigned s0 = s1 + p0;
    if (s3 >= need && next < need) { *out_b = (unsigned)(lane * 4 + 3); *out_above = next; }
    if (s2 >= need && s3 < need)   { *out_b = (unsigned)(lane * 4 + 2); *out_above = s3; }
    if (s1 >= need && s2 < need)   { *out_b = (unsigned)(lane * 4 + 1); *out_above = s2; }
    if (s0 >= need && s1 < need)   { *out_b = (unsigned)(lane * 4 + 0); *out_above = s1; }
}

// ---------------------------------------------------------------------------
// Kernel 1: fused LN for BOTH inputs, wave-per-row, barrier-free.
// ---------------------------------------------------------------------------
__global__ __launch_bounds__(256) void ln_all(
    const float* __restrict__ prior, const float* __restrict__ clip,
    const float* __restrict__ g1, const float* __restrict__ b1,
    const float* __restrict__ g2, const float* __restrict__ b2,
    __hip_bfloat16* __restrict__ x1n, __hip_bfloat16* __restrict__ x2n,
    double* __restrict__ stats1, double* __restrict__ wq,
    double* __restrict__ consts) {
    const int bid = blockIdx.x;
    const int tid = threadIdx.x;
    const int lane = tid & 63, wave = tid >> 6;

    if (bid < N1C / 4) {
        const int row = bid * 4 + wave;
        const float* xr = prior + (size_t)row * DIMN;
        float4 xv[4], gv[4], bv[4];
        #pragma unroll
        for (int j = 0; j < 4; ++j) {
            xv[j] = *(const float4*)(xr + lane * 4 + j * 256);
            gv[j] = *(const float4*)(g1 + lane * 4 + j * 256);
            bv[j] = *(const float4*)(b1 + lane * 4 + j * 256);
        }
        double s = 0.0, s2 = 0.0;
        #pragma unroll
        for (int j = 0; j < 4; ++j) {
            double a = xv[j].x, b = xv[j].y, c = xv[j].z, d = xv[j].w;
            s += (a + b) + (c + d);
            s2 += (a * a + b * b) + (c * c + d * d);
        }
        s = wave_reduce_sum_d(s);
        s2 = wave_reduce_sum_d(s2);
        double mu, rstd;
        if (lane == 0) {
            mu = s / (double)DIMN;
            double var = s2 / (double)DIMN - mu * mu;
            rstd = 1.0 / sqrt(var + 1e-5);
        }
        mu = __shfl(mu, 0, 64);
        rstd = __shfl(rstd, 0, 64);

        double y[16];
        double q = 0.0;
        #pragma unroll
        for (int j = 0; j < 4; ++j) {
            double y0 = ((double)xv[j].x - mu) * rstd * (double)gv[j].x + (double)bv[j].x;
            double y1 = ((double)xv[j].y - mu) * rstd * (double)gv[j].y + (double)bv[j].y;
            double y2 = ((double)xv[j].z - mu) * rstd * (double)gv[j].z + (double)bv[j].z;
            double y3 = ((double)xv[j].w - mu) * rstd * (double)gv[j].w + (double)bv[j].w;
            y[j * 4 + 0] = y0; y[j * 4 + 1] = y1; y[j * 4 + 2] = y2; y[j * 4 + 3] = y3;
            q += (y0 * y0 + y1 * y1) + (y2 * y2 + y3 * y3);
        }
        q = wave_reduce_sum_d(q);
        double invn;
        if (lane == 0) {
            invn = 1.0 / fmax(sqrt(q), 1e-8);
            stats1[(size_t)row * 3 + 0] = mu;
            stats1[(size_t)row * 3 + 1] = rstd;
            stats1[(size_t)row * 3 + 2] = invn;
        }
        invn = __shfl(invn, 0, 64);

        ushort_t* dst = (ushort_t*)x1n + (size_t)row * DIMN;
        #pragma unroll
        for (int j = 0; j < 4; ++j) {
            uint2 pk;
            pk.x = (unsigned)f2bf((float)(y[j * 4 + 0] * invn)) |
                   ((unsigned)f2bf((float)(y[j * 4 + 1] * invn)) << 16);
            pk.y = (unsigned)f2bf((float)(y[j * 4 + 2] * invn)) |
                   ((unsigned)f2bf((float)(y[j * 4 + 3] * invn)) << 16);
            *(uint2*)(dst + lane * 4 + j * 256) = pk;
        }
    } else {
        const int q = (bid - N1C / 4) * 4 + wave;
        const float* xr = clip + (size_t)q * DIMN;
        float4 xv[4];
        #pragma unroll
        for (int j = 0; j < 4; ++j)
            xv[j] = *(const float4*)(xr + lane * 4 + j * 256);

        double s = 0.0, s2 = 0.0;
        #pragma unroll
        for (int j = 0; j < 4; ++j) {
            double a = xv[j].x, b = xv[j].y, c = xv[j].z, d = xv[j].w;
            s += (a + b) + (c + d);
            s2 += (a * a + b * b) + (c * c + d * d);
        }
        s = wave_reduce_sum_d(s);
        s2 = wave_reduce_sum_d(s2);
        double mu, rstd;
        if (lane == 0) {
            mu = s / (double)DIMN;
            double var = s2 / (double)DIMN - mu * mu;
            rstd = 1.0 / sqrt(var + 1e-5);
        }
        mu = __shfl(mu, 0, 64);
        rstd = __shfl(rstd, 0, 64);

        double yv[16];
        double qq = 0.0;
        #pragma unroll
        for (int j = 0; j < 4; ++j) {
            const float4 g2v = *(const float4*)(g2 + lane * 4 + j * 256);
            const float4 b2v = *(const float4*)(b2 + lane * 4 + j * 256);
            double y0 = ((double)xv[j].x - mu) * rstd * (double)g2v.x + (double)b2v.x;
            double y1 = ((double)xv[j].y - mu) * rstd * (double)g2v.y + (double)b2v.y;
            double y2 = ((double)xv[j].z - mu) * rstd * (double)g2v.z + (double)b2v.z;
            double y3 = ((double)xv[j].w - mu) * rstd * (double)g2v.w + (double)b2v.w;
            yv[j * 4 + 0] = y0; yv[j * 4 + 1] = y1;
            yv[j * 4 + 2] = y2; yv[j * 4 + 3] = y3;
            qq += (y0 * y0 + y1 * y1) + (y2 * y2 + y3 * y3);
        }
        qq = wave_reduce_sum_d(qq);
        double invn;
        if (lane == 0) invn = 1.0 / fmax(sqrt(qq), 1e-8);
        invn = __shfl(invn, 0, 64);

        double c1 = 0.0, c2 = 0.0;
        ushort_t* dst = (ushort_t*)x2n + (size_t)q * DIMN;
        double* wrow = wq + (size_t)q * DIMN;
        #pragma unroll
        for (int j = 0; j < 4; ++j) {
            double y0 = yv[j * 4 + 0] * invn, y1 = yv[j * 4 + 1] * invn;
            double y2 = yv[j * 4 + 2] * invn, y3 = yv[j * 4 + 3] * invn;
            uint2 pk;
            pk.x = (unsigned)f2bf((float)y0) | ((unsigned)f2bf((float)y1) << 16);
            pk.y = (unsigned)f2bf((float)y2) | ((unsigned)f2bf((float)y3) << 16);
            *(uint2*)(dst + lane * 4 + j * 256) = pk;

            const float4 g1v = *(const float4*)(g1 + lane * 4 + j * 256);
            const float4 b1v = *(const float4*)(b1 + lane * 4 + j * 256);
            double w0 = y0 * (double)g1v.x, w1 = y1 * (double)g1v.y;
            double w2 = y2 * (double)g1v.z, w3 = y3 * (double)g1v.w;
            double* wp = wrow + lane * 4 + j * 256;
            double2 t0; t0.x = w0; t0.y = w1;
            double2 t1; t1.x = w2; t1.y = w3;
            *(double2*)(wp) = t0;
            *(double2*)(wp + 2) = t1;
            c1 += ((double)b1v.x * y0 + (double)b1v.y * y1) +
                  ((double)b1v.z * y2 + (double)b1v.w * y3);
            c2 += (w0 + w1) + (w2 + w3);
        }
        c1 = wave_reduce_sum_d(c1);
        c2 = wave_reduce_sum_d(c2);
        if (lane == 0) {
            consts[(size_t)q * 2 + 0] = c1;
            consts[(size_t)q * 2 + 1] = c2;
        }
    }
}

// ---------------------------------------------------------------------------
// Kernel 2: candidate GEMM via MFMA (m97 structure, BK=64, XCD swizzle),
// LDS-staged coalesced epilogue.
// ---------------------------------------------------------------------------
#define BM 128
#define BN 128
#define BKG 64
#define CPAD 136

__global__ __launch_bounds__(256) void sim_gemm(
    const __hip_bfloat16* __restrict__ x2n, const __hip_bfloat16* __restrict__ x1n,
    ushort_t* __restrict__ simkey) {
    __shared__ __align__(16) ushort_t smem[BM * CPAD];
    ushort_t (*As)[BKG] = (ushort_t(*)[BKG])smem;
    ushort_t (*Bs)[BKG] = (ushort_t(*)[BKG])(smem + BM * BKG);

    const int bid = blockIdx.x;
    const int l = (bid & 7) * 128 + (bid >> 3);
    const int q0 = (l & 3) * BM;
    const int n0 = (l >> 2) * BN;

    const int tid = threadIdx.x;
    const int ln = tid & 63, wv = tid >> 6;
    const int wr = wv >> 1, wc = wv & 1;

    const int st_r = ln >> 3;
    const int st_c = (ln & 7) * 8;

    const ushort_t* Ab = (const ushort_t*)x2n;
    const ushort_t* Bb = (const ushort_t*)x1n;

    f32x4 acc[4][4];
    #pragma unroll
    for (int m = 0; m < 4; ++m)
        #pragma unroll
        for (int n = 0; n < 4; ++n) acc[m][n] = (f32x4)0.0f;

    const int lr = ln & 15;
    const int lk = (ln >> 4) * 8;

    for (int kt = 0; kt < DIMN; kt += BKG) {
        #pragma unroll
        for (int i = 0; i < 4; ++i) {
            int ci = i * 4 + wv;
            int row = ci * 8 + st_r;
            gload_lds16(Ab + (size_t)(q0 + row) * DIMN + kt + st_c,
                        (char*)&As[0][0] + ci * 1024);
            gload_lds16(Bb + (size_t)(n0 + row) * DIMN + kt + st_c,
                        (char*)&Bs[0][0] + ci * 1024);
        }
        __syncthreads();

        short8 af[4][2], bfr[4][2];
        #pragma unroll
        for (int m = 0; m < 4; ++m) {
            af[m][0] = *(const short8*)&As[wr * 64 + m * 16 + lr][lk];
            af[m][1] = *(const short8*)&As[wr * 64 + m * 16 + lr][32 + lk];
        }
        #pragma unroll
        for (int n = 0; n < 4; ++n) {
            bfr[n][0] = *(const short8*)&Bs[wc * 64 + n * 16 + lr][lk];
            bfr[n][1] = *(const short8*)&Bs[wc * 64 + n * 16 + lr][32 + lk];
        }
        #pragma unroll
        for (int m = 0; m < 4; ++m)
            #pragma unroll
            for (int n = 0; n < 4; ++n) {
                acc[m][n] = __builtin_amdgcn_mfma_f32_16x16x32_bf16(
                    af[m][0], bfr[n][0], acc[m][n], 0, 0, 0);
                acc[m][n] = __builtin_amdgcn_mfma_f32_16x16x32_bf16(
                    af[m][1], bfr[n][1], acc[m][n], 0, 0, 0);
            }
        __syncthreads();
    }

    const int crow = (ln >> 4) * 4;
    #pragma unroll
    for (int m = 0; m < 4; ++m) {
        #pragma unroll
        for (int n = 0; n < 4; ++n) {
            int col_l = wc * 64 + n * 16 + lr;
            #pragma unroll
            for (int r = 0; r < 4; ++r) {
                int row_l = wr * 64 + m * 16 + crow + r;
                smem[row_l * CPAD + col_l] =
                    (ushort_t)key_of_bf16((unsigned)f2bf(acc[m][n][r]));
            }
        }
    }
    __syncthreads();
    #pragma unroll
    for (int i = 0; i < 8; ++i) {
        int idx = i * 256 + tid;
        int row = idx >> 4, c16 = idx & 15;
        uint4 v = *(const uint4*)(smem + row * CPAD + c16 * 8);
        *(uint4*)(simkey + (size_t)(q0 + row) * N1C + n0 + c16 * 8) = v;
    }
}

// ---------------------------------------------------------------------------
// Kernel 3a: per-(q, segment) top->=MCAND via 2-pass RADIX-SELECT.
// Keys in registers; pass A: high-byte histogram; pass B: low-byte within
// the crossing bin. 5 barriers total (vs 16-pass bisection's 16).
// Threshold identical to bisection: largest T with count(key>=T) >= MCAND.
// ---------------------------------------------------------------------------
__global__ __launch_bounds__(256) void seg_topk_rad(
    const ushort_t* __restrict__ simkey, unsigned* __restrict__ segcand,
    int* __restrict__ segcnt) {
    const int bid = blockIdx.x;
    const int seg = bid & 3, q = bid >> 2;
    const int tid = threadIdx.x;
    const int lane = tid & 63, wave = tid >> 6;

    __shared__ unsigned histA[256], histB[256];
    __shared__ unsigned scnt;
    __shared__ unsigned hb_sh, above_sh, lb_sh, dummy_sh;

    histA[tid] = 0;
    histB[tid] = 0;
    if (tid == 0) scnt = 0;

    const unsigned* rowPair =
        (const unsigned*)(simkey + (size_t)q * N1C) + seg * (SEG / 2);
    unsigned kreg[16];
    #pragma unroll
    for (int s = 0; s < 16; ++s)
        kreg[s] = rowPair[s * 256 + tid];
    __syncthreads();

    // pass A: high-byte histogram
    #pragma unroll
    for (int s = 0; s < 16; ++s) {
        atomicAdd(&histA[(kreg[s] >> 8) & 0xFFu], 1u);
        atomicAdd(&histA[kreg[s] >> 24], 1u);
    }
    __syncthreads();
    if (wave == 0) radix_scan_w0(histA, MCAND, lane, &hb_sh, &above_sh);
    __syncthreads();
    const unsigned hb = hb_sh;
    const unsigned need2 = MCAND - above_sh;

    // pass B: low-byte histogram within bin hb
    #pragma unroll
    for (int s = 0; s < 16; ++s) {
        unsigned k0 = kreg[s] & 0xFFFFu, k1 = kreg[s] >> 16;
        if ((k0 >> 8) == hb) atomicAdd(&histB[k0 & 0xFFu], 1u);
        if ((k1 >> 8) == hb) atomicAdd(&histB[k1 & 0xFFu], 1u);
    }
    __syncthreads();
    if (wave == 0) radix_scan_w0(histB, need2, lane, &lb_sh, &dummy_sh);
    __syncthreads();
    const unsigned thr = (hb << 8) | lb_sh;

    // collect (incl. ties), cap SEGCAP — same semantics as all prior rounds
    #pragma unroll
    for (int s = 0; s < 16; ++s) {
        unsigned k0 = kreg[s] & 0xFFFFu, k1 = kreg[s] >> 16;
        unsigned e0 = (unsigned)(seg * SEG + (s * 256 + tid) * 2);
        if (k0 >= thr) {
            unsigned p = atomicAdd(&scnt, 1u);
            if (p < SEGCAP) segcand[(size_t)bid * SEGCAP + p] = (k0 << 16) | e0;
        }
        if (k1 >= thr) {
            unsigned p = atomicAdd(&scnt, 1u);
            if (p < SEGCAP) segcand[(size_t)bid * SEGCAP + p] = (k1 << 16) | (e0 + 1);
        }
    }
    __syncthreads();
    if (tid == 0) segcnt[bid] = (int)(scnt < SEGCAP ? scnt : SEGCAP);
}

// ---------------------------------------------------------------------------
// Kernel 3b: merge 4 segments' pools via the same 2-pass radix-select.
// ---------------------------------------------------------------------------
__global__ __launch_bounds__(256) void merge_cand(
    const unsigned* __restrict__ segcand, const int* __restrict__ segcnt,
    int* __restrict__ cand, int* __restrict__ cand_cnt) {
    const int q = blockIdx.x;
    const int tid = threadIdx.x;
    const int lane = tid & 63, wave = tid >> 6;

    __shared__ unsigned buf[4 * SEGCAP];
    __shared__ int offs[5];
    __shared__ unsigned histA[256], histB[256];
    __shared__ unsigned cnt;
    __shared__ unsigned hb_sh, above_sh, lb_sh, dummy_sh;

    histA[tid] = 0;
    histB[tid] = 0;
    if (tid == 0) {
        int o = 0;
        #pragma unroll
        for (int s = 0; s < 4; ++s) { offs[s] = o; o += segcnt[q * 4 + s]; }
        offs[4] = o;
        cnt = 0;
    }
    __syncthreads();
    const int tot = offs[4];
    #pragma unroll
    for (int s = 0; s < 4; ++s) {
        int cs = offs[s + 1] - offs[s];
        for (int i = tid; i < cs; i += 256)
            buf[offs[s] + i] = segcand[(size_t)(q * 4 + s) * SEGCAP + i];
    }
    __syncthreads();

    // register copies of this thread's <=4 pool entries
    unsigned e0 = 0, e1 = 0, e2 = 0, e3 = 0;
    const bool h0 = tid < tot, h1 = tid + 256 < tot,
               h2 = tid + 512 < tot, h3 = tid + 768 < tot;
    if (h0) e0 = buf[tid];
    if (h1) e1 = buf[tid + 256];
    if (h2) e2 = buf[tid + 512];
    if (h3) e3 = buf[tid + 768];

    // pass A
    if (h0) atomicAdd(&histA[e0 >> 24], 1u);
    if (h1) atomicAdd(&histA[e1 >> 24], 1u);
    if (h2) atomicAdd(&histA[e2 >> 24], 1u);
    if (h3) atomicAdd(&histA[e3 >> 24], 1u);
    __syncthreads();
    if (wave == 0) radix_scan_w0(histA, MCAND, lane, &hb_sh, &above_sh);
    __syncthreads();
    const unsigned hb = hb_sh;
    const unsigned need2 = MCAND - above_sh;

    // pass B
    if (h0 && (e0 >> 24) == hb) atomicAdd(&histB[(e0 >> 16) & 0xFFu], 1u);
    if (h1 && (e1 >> 24) == hb) atomicAdd(&histB[(e1 >> 16) & 0xFFu], 1u);
    if (h2 && (e2 >> 24) == hb) atomicAdd(&histB[(e2 >> 16) & 0xFFu], 1u);
    if (h3 && (e3 >> 24) == hb) atomicAdd(&histB[(e3 >> 16) & 0xFFu], 1u);
    __syncthreads();
    if (wave == 0) radix_scan_w0(histB, need2, lane, &lb_sh, &dummy_sh);
    __syncthreads();
    const unsigned thr = (hb << 8) | lb_sh;

    if (h0 && (e0 >> 16) >= thr) {
        unsigned p = atomicAdd(&cnt, 1u);
        if (p < CAP) cand[(size_t)q * CAP + p] = (int)(e0 & 0xFFFFu);
    }
    if (h1 && (e1 >> 16) >= thr) {
        unsigned p = atomicAdd(&cnt, 1u);
        if (p < CAP) cand[(size_t)q * CAP + p] = (int)(e1 & 0xFFFFu);
    }
    if (h2 && (e2 >> 16) >= thr) {
        unsigned p = atomicAdd(&cnt, 1u);
        if (p < CAP) cand[(size_t)q * CAP + p] = (int)(e2 & 0xFFFFu);
    }
    if (h3 && (e3 >> 16) >= thr) {
        unsigned p = atomicAdd(&cnt, 1u);
        if (p < CAP) cand[(size_t)q * CAP + p] = (int)(e3 & 0xFFFFu);
    }
    __syncthreads();
    if (tid == 0) cand_cnt[q] = (int)(cnt < CAP ? cnt : CAP);
}

// ---------------------------------------------------------------------------
// Kernel 4a: fp64 factorized scoring, 4 candidates in flight per wave.
// ---------------------------------------------------------------------------
__global__ __launch_bounds__(256) void score_cand(
    const float* __restrict__ x1, const double* __restrict__ stats1,
    const double* __restrict__ wq, const double* __restrict__ consts,
    const int* __restrict__ cand, const int* __restrict__ cand_cnt,
    double* __restrict__ vals) {
    const int q = blockIdx.x, chunk = blockIdx.y;
    const int tid = threadIdx.x;
    const int lane = tid & 63, wv = tid >> 6;
    const int cnt = cand_cnt[q];
    const int cbase = chunk * 16;
    if (cbase >= cnt) return;

    const double C1 = consts[(size_t)q * 2 + 0];
    const double C2 = consts[(size_t)q * 2 + 1];

    const double* w = wq + (size_t)q * DIMN;
    double wr[16];
    #pragma unroll
    for (int j = 0; j < 4; ++j) {
        double2 a = *(const double2*)(w + lane * 4 + j * 256);
        double2 b = *(const double2*)(w + lane * 4 + j * 256 + 2);
        wr[j * 4 + 0] = a.x; wr[j * 4 + 1] = a.y;
        wr[j * 4 + 2] = b.x; wr[j * 4 + 3] = b.y;
    }

    const int cA = cbase + wv;
    const int cB = cA + 4;
    const int cC = cA + 8;
    const int cD = cA + 12;
    const bool hA = cA < cnt, hB = cB < cnt, hC = cC < cnt, hD = cD < cnt;
    if (!hA) return;
    const int nA = cand[(size_t)q * CAP + cA];
    const int nB = hB ? cand[(size_t)q * CAP + cB] : nA;
    const int nC = hC ? cand[(size_t)q * CAP + cC] : nA;
    const int nD = hD ? cand[(size_t)q * CAP + cD] : nA;
    const float* xrA = x1 + (size_t)nA * DIMN;
    const float* xrB = x1 + (size_t)nB * DIMN;
    const float* xrC = x1 + (size_t)nC * DIMN;
    const float* xrD = x1 + (size_t)nD * DIMN;

    double aA = 0.0, aB = 0.0, aC = 0.0, aD = 0.0;
    #pragma unroll
    for (int j = 0; j < 4; ++j) {
        float4 xa = *(const float4*)(xrA + lane * 4 + j * 256);
        float4 xb = *(const float4*)(xrB + lane * 4 + j * 256);
        float4 xc = *(const float4*)(xrC + lane * 4 + j * 256);
        float4 xd = *(const float4*)(xrD + lane * 4 + j * 256);
        aA += (double)xa.x * wr[j * 4 + 0] + (double)xa.y * wr[j * 4 + 1] +
              (double)xa.z * wr[j * 4 + 2] + (double)xa.w * wr[j * 4 + 3];
        aB += (double)xb.x * wr[j * 4 + 0] + (double)xb.y * wr[j * 4 + 1] +
              (double)xb.z * wr[j * 4 + 2] + (double)xb.w * wr[j * 4 + 3];
        aC += (double)xc.x * wr[j * 4 + 0] + (double)xc.y * wr[j * 4 + 1] +
              (double)xc.z * wr[j * 4 + 2] + (double)xc.w * wr[j * 4 + 3];
        aD += (double)xd.x * wr[j * 4 + 0] + (double)xd.y * wr[j * 4 + 1] +
              (double)xd.z * wr[j * 4 + 2] + (double)xd.w * wr[j * 4 + 3];
    }
    aA = wave_reduce_sum_d(aA);
    aB = wave_reduce_sum_d(aB);
    aC = wave_reduce_sum_d(aC);
    aD = wave_reduce_sum_d(aD);
    if (lane == 0) {
        {
            const double mu1 = stats1[(size_t)nA * 3 + 0];
            const double rstd1 = stats1[(size_t)nA * 3 + 1];
            const double invn1 = stats1[(size_t)nA * 3 + 2];
            vals[(size_t)q * CAP + cA] = (rstd1 * invn1) * (aA - mu1 * C2) + invn1 * C1;
        }
        if (hB) {
            const double mu1 = stats1[(size_t)nB * 3 + 0];
            const double rstd1 = stats1[(size_t)nB * 3 + 1];
            const double invn1 = stats1[(size_t)nB * 3 + 2];
            vals[(size_t)q * CAP + cB] = (rstd1 * invn1) * (aB - mu1 * C2) + invn1 * C1;
        }
        if (hC) {
            const double mu1 = stats1[(size_t)nC * 3 + 0];
            const double rstd1 = stats1[(size_t)nC * 3 + 1];
            const double invn1 = stats1[(size_t)nC * 3 + 2];
            vals[(size_t)q * CAP + cC] = (rstd1 * invn1) * (aC - mu1 * C2) + invn1 * C1;
        }
        if (hD) {
            const double mu1 = stats1[(size_t)nD * 3 + 0];
            const double rstd1 = stats1[(size_t)nD * 3 + 1];
            const double invn1 = stats1[(size_t)nD * 3 + 2];
            vals[(size_t)q * CAP + cD] = (rstd1 * invn1) * (aD - mu1 * C2) + invn1 * C1;
        }
    }
}

// ---------------------------------------------------------------------------
// Kernel 4b: exact top-64 selection (value desc, idx asc). One wave per q.
// ---------------------------------------------------------------------------
__global__ __launch_bounds__(64) void select_topk(
    const double* __restrict__ vals, const int* __restrict__ cand,
    const int* __restrict__ cand_cnt, float* __restrict__ out) {
    const int q = blockIdx.x;
    const int lane = threadIdx.x;
    const int cnt = cand_cnt[q];

    double v0 = (lane < cnt)       ? vals[(size_t)q * CAP + lane]       : -1e300;
    double v1 = (lane + 64 < cnt)  ? vals[(size_t)q * CAP + lane + 64]  : -1e300;
    double v2 = (lane + 128 < cnt) ? vals[(size_t)q * CAP + lane + 128] : -1e300;
    double v3 = (lane + 192 < cnt) ? vals[(size_t)q * CAP + lane + 192] : -1e300;
    int i0 = (lane < cnt)       ? cand[(size_t)q * CAP + lane]       : 0x7FFFFFFF;
    int i1 = (lane + 64 < cnt)  ? cand[(size_t)q * CAP + lane + 64]  : 0x7FFFFFFF;
    int i2 = (lane + 128 < cnt) ? cand[(size_t)q * CAP + lane + 128] : 0x7FFFFFFF;
    int i3 = (lane + 192 < cnt) ? cand[(size_t)q * CAP + lane + 192] : 0x7FFFFFFF;

    for (int k = 0; k < KTOP; ++k) {
        bool a01 = (v0 > v1) || (v0 == v1 && i0 < i1);
        double va = a01 ? v0 : v1; int ia = a01 ? i0 : i1; int sa = a01 ? 0 : 1;
        bool a23 = (v2 > v3) || (v2 == v3 && i2 < i3);
        double vb = a23 ? v2 : v3; int ib = a23 ? i2 : i3; int sb = a23 ? 2 : 3;
        bool ab = (va > vb) || (va == vb && ia < ib);
        double mv = ab ? va : vb; int mi = ab ? ia : ib; int slot = ab ? sa : sb;
        int owner = lane;
        #pragma unroll
        for (int off = 32; off > 0; off >>= 1) {
            double ov = __shfl_down(mv, off, 64);
            int oi = __shfl_down(mi, off, 64);
            int oo = __shfl_down(owner, off, 64);
            int os = __shfl_down(slot, off, 64);
            bool take = (ov > mv) || (ov == mv && oi < mi);
            if (take) { mv = ov; mi = oi; owner = oo; slot = os; }
        }
        int wown = __shfl(owner, 0, 64);
        int wslot = __shfl(slot, 0, 64);
        int wmi = __shfl(mi, 0, 64);
        if (lane == 0) out[(size_t)q * KTOP + k] = (float)wmi * (1.0f / 32768.0f);
        if (lane == wown) {
            v0 = (wslot == 0) ? -1e300 : v0;
            v1 = (wslot == 1) ? -1e300 : v1;
            v2 = (wslot == 2) ? -1e300 : v2;
            v3 = (wslot == 3) ? -1e300 : v3;
        }
    }
}

// ---------------------------------------------------------------------------
extern "C" void kernel_launch(void* const* d_in, const int* in_sizes, int n_in,
                              void* d_out, int out_size, void* d_ws, size_t ws_size,
                              hipStream_t stream) {
    const float* prior = (const float*)d_in[0];
    const float* clip  = (const float*)d_in[1];
    const float* g1    = (const float*)d_in[2];
    const float* b1    = (const float*)d_in[3];
    const float* g2    = (const float*)d_in[4];
    const float* b2    = (const float*)d_in[5];
    float* out = (float*)d_out;

    char* ws = (char*)d_ws;
    size_t off = 0;
    double* stats1 = (double*)(ws + off); off += (size_t)N1C * 3 * sizeof(double);
    __hip_bfloat16* x1n = (__hip_bfloat16*)(ws + off); off += (size_t)N1C * DIMN * 2;
    __hip_bfloat16* x2n = (__hip_bfloat16*)(ws + off); off += (size_t)N2C * DIMN * 2;
    ushort_t* simkey = (ushort_t*)(ws + off); off += (size_t)N2C * N1C * 2;
    unsigned* segcand = (unsigned*)(ws + off); off += (size_t)N2C * 4 * SEGCAP * 4;
    int* segcnt = (int*)(ws + off); off += (size_t)N2C * 4 * sizeof(int);
    int* cand = (int*)(ws + off); off += (size_t)N2C * CAP * sizeof(int);
    int* cand_cnt = (int*)(ws + off); off += (size_t)N2C * sizeof(int);
    double* wq = (double*)(ws + off); off += (size_t)N2C * DIMN * sizeof(double);
    double* consts = (double*)(ws + off); off += (size_t)N2C * 2 * sizeof(double);
    double* vals = (double*)(ws + off); off += (size_t)N2C * CAP * sizeof(double);

    ln_all<<<N1C / 4 + N2C / 4, 256, 0, stream>>>(
        prior, clip, g1, b1, g2, b2, x1n, x2n, stats1, wq, consts);

    sim_gemm<<<(N1C / BN) * (N2C / BM), 256, 0, stream>>>(x2n, x1n, simkey);

    seg_topk_rad<<<N2C * 4, 256, 0, stream>>>(simkey, segcand, segcnt);
    merge_cand<<<N2C, 256, 0, stream>>>(segcand, segcnt, cand, cand_cnt);

    dim3 gs(N2C, 16);
    score_cand<<<gs, 256, 0, stream>>>(prior, stats1, wq, consts, cand, cand_cnt, vals);
    select_topk<<<N2C, 64, 0, stream>>>(vals, cand, cand_cnt, out);
}

// Round 15
// 188.664 us; speedup vs baseline: 1.4204x; 1.0571x over previous
//
#include <hip/hip_runtime.h>
#include <hip/hip_bf16.h>
#include <stdint.h>

#define DIMN 1024
#define N1C 32768
#define N2C 512
#define KTOP 64
#define MCAND 80
#define CAP 256
#define SEG 8192
#define SEGCAP 256

typedef unsigned short ushort_t;
typedef __attribute__((ext_vector_type(8))) short short8;
typedef __attribute__((ext_vector_type(4))) float f32x4;

__device__ __forceinline__ double wave_reduce_sum_d(double v) {
    #pragma unroll
    for (int off = 32; off > 0; off >>= 1)
        v += __shfl_down(v, off, 64);
    return v;
}

__device__ __forceinline__ void gload_lds16(const void* g, void* l) {
    __builtin_amdgcn_global_load_lds(
        (const __attribute__((address_space(1))) unsigned*)g,
        (__attribute__((address_space(3))) unsigned*)l, 16, 0, 0);
}

__device__ __forceinline__ ushort_t f2bf(float f) {
    __hip_bfloat16 h = __float2bfloat16(f);
    return *reinterpret_cast<ushort_t*>(&h);
}

__device__ __forceinline__ unsigned key_of_bf16(unsigned u16) {
    return (u16 & 0x8000u) ? (0xFFFFu & ~u16) : (u16 | 0x8000u);
}

// Wave-0 radix scan over a 256-bin LDS histogram (see R14).
__device__ __forceinline__ void radix_scan_w0(
    const unsigned* hist, unsigned need, int lane,
    unsigned* out_b, unsigned* out_above) {
    unsigned p0 = hist[lane * 4 + 0], p1 = hist[lane * 4 + 1];
    unsigned p2 = hist[lane * 4 + 2], p3 = hist[lane * 4 + 3];
    unsigned suf = p0 + p1 + p2 + p3;
    #pragma unroll
    for (int off = 1; off < 64; off <<= 1) {
        unsigned o = __shfl_down(suf, off, 64);
        if (lane + off < 64) suf += o;
    }
    unsigned next = __shfl_down(suf, 1, 64);
    if (lane == 63) next = 0u;
    unsigned s3 = next + p3;
    unsigned s2 = s3 + p2;
    unsigned s1 = s2 + p1;
    unsigned s0 = s1 + p0;
    if (s3 >= need && next < need) { *out_b = (unsigned)(lane * 4 + 3); *out_above = next; }
    if (s2 >= need && s3 < need)   { *out_b = (unsigned)(lane * 4 + 2); *out_above = s3; }
    if (s1 >= need && s2 < need)   { *out_b = (unsigned)(lane * 4 + 1); *out_above = s2; }
    if (s0 >= need && s1 < need)   { *out_b = (unsigned)(lane * 4 + 0); *out_above = s1; }
}

// ---------------------------------------------------------------------------
// Kernel 1: fused LN for BOTH inputs, wave-per-row, barrier-free.
// ---------------------------------------------------------------------------
__global__ __launch_bounds__(256) void ln_all(
    const float* __restrict__ prior, const float* __restrict__ clip,
    const float* __restrict__ g1, const float* __restrict__ b1,
    const float* __restrict__ g2, const float* __restrict__ b2,
    __hip_bfloat16* __restrict__ x1n, __hip_bfloat16* __restrict__ x2n,
    double* __restrict__ stats1, double* __restrict__ wq,
    double* __restrict__ consts) {
    const int bid = blockIdx.x;
    const int tid = threadIdx.x;
    const int lane = tid & 63, wave = tid >> 6;

    if (bid < N1C / 4) {
        const int row = bid * 4 + wave;
        const float* xr = prior + (size_t)row * DIMN;
        float4 xv[4], gv[4], bv[4];
        #pragma unroll
        for (int j = 0; j < 4; ++j) {
            xv[j] = *(const float4*)(xr + lane * 4 + j * 256);
            gv[j] = *(const float4*)(g1 + lane * 4 + j * 256);
            bv[j] = *(const float4*)(b1 + lane * 4 + j * 256);
        }
        double s = 0.0, s2 = 0.0;
        #pragma unroll
        for (int j = 0; j < 4; ++j) {
            double a = xv[j].x, b = xv[j].y, c = xv[j].z, d = xv[j].w;
            s += (a + b) + (c + d);
            s2 += (a * a + b * b) + (c * c + d * d);
        }
        s = wave_reduce_sum_d(s);
        s2 = wave_reduce_sum_d(s2);
        double mu, rstd;
        if (lane == 0) {
            mu = s / (double)DIMN;
            double var = s2 / (double)DIMN - mu * mu;
            rstd = 1.0 / sqrt(var + 1e-5);
        }
        mu = __shfl(mu, 0, 64);
        rstd = __shfl(rstd, 0, 64);

        double y[16];
        double q = 0.0;
        #pragma unroll
        for (int j = 0; j < 4; ++j) {
            double y0 = ((double)xv[j].x - mu) * rstd * (double)gv[j].x + (double)bv[j].x;
            double y1 = ((double)xv[j].y - mu) * rstd * (double)gv[j].y + (double)bv[j].y;
            double y2 = ((double)xv[j].z - mu) * rstd * (double)gv[j].z + (double)bv[j].z;
            double y3 = ((double)xv[j].w - mu) * rstd * (double)gv[j].w + (double)bv[j].w;
            y[j * 4 + 0] = y0; y[j * 4 + 1] = y1; y[j * 4 + 2] = y2; y[j * 4 + 3] = y3;
            q += (y0 * y0 + y1 * y1) + (y2 * y2 + y3 * y3);
        }
        q = wave_reduce_sum_d(q);
        double invn;
        if (lane == 0) {
            invn = 1.0 / fmax(sqrt(q), 1e-8);
            stats1[(size_t)row * 3 + 0] = mu;
            stats1[(size_t)row * 3 + 1] = rstd;
            stats1[(size_t)row * 3 + 2] = invn;
        }
        invn = __shfl(invn, 0, 64);

        ushort_t* dst = (ushort_t*)x1n + (size_t)row * DIMN;
        #pragma unroll
        for (int j = 0; j < 4; ++j) {
            uint2 pk;
            pk.x = (unsigned)f2bf((float)(y[j * 4 + 0] * invn)) |
                   ((unsigned)f2bf((float)(y[j * 4 + 1] * invn)) << 16);
            pk.y = (unsigned)f2bf((float)(y[j * 4 + 2] * invn)) |
                   ((unsigned)f2bf((float)(y[j * 4 + 3] * invn)) << 16);
            *(uint2*)(dst + lane * 4 + j * 256) = pk;
        }
    } else {
        const int q = (bid - N1C / 4) * 4 + wave;
        const float* xr = clip + (size_t)q * DIMN;
        float4 xv[4];
        #pragma unroll
        for (int j = 0; j < 4; ++j)
            xv[j] = *(const float4*)(xr + lane * 4 + j * 256);

        double s = 0.0, s2 = 0.0;
        #pragma unroll
        for (int j = 0; j < 4; ++j) {
            double a = xv[j].x, b = xv[j].y, c = xv[j].z, d = xv[j].w;
            s += (a + b) + (c + d);
            s2 += (a * a + b * b) + (c * c + d * d);
        }
        s = wave_reduce_sum_d(s);
        s2 = wave_reduce_sum_d(s2);
        double mu, rstd;
        if (lane == 0) {
            mu = s / (double)DIMN;
            double var = s2 / (double)DIMN - mu * mu;
            rstd = 1.0 / sqrt(var + 1e-5);
        }
        mu = __shfl(mu, 0, 64);
        rstd = __shfl(rstd, 0, 64);

        double yv[16];
        double qq = 0.0;
        #pragma unroll
        for (int j = 0; j < 4; ++j) {
            const float4 g2v = *(const float4*)(g2 + lane * 4 + j * 256);
            const float4 b2v = *(const float4*)(b2 + lane * 4 + j * 256);
            double y0 = ((double)xv[j].x - mu) * rstd * (double)g2v.x + (double)b2v.x;
            double y1 = ((double)xv[j].y - mu) * rstd * (double)g2v.y + (double)b2v.y;
            double y2 = ((double)xv[j].z - mu) * rstd * (double)g2v.z + (double)b2v.z;
            double y3 = ((double)xv[j].w - mu) * rstd * (double)g2v.w + (double)b2v.w;
            yv[j * 4 + 0] = y0; yv[j * 4 + 1] = y1;
            yv[j * 4 + 2] = y2; yv[j * 4 + 3] = y3;
            qq += (y0 * y0 + y1 * y1) + (y2 * y2 + y3 * y3);
        }
        qq = wave_reduce_sum_d(qq);
        double invn;
        if (lane == 0) invn = 1.0 / fmax(sqrt(qq), 1e-8);
        invn = __shfl(invn, 0, 64);

        double c1 = 0.0, c2 = 0.0;
        ushort_t* dst = (ushort_t*)x2n + (size_t)q * DIMN;
        double* wrow = wq + (size_t)q * DIMN;
        #pragma unroll
        for (int j = 0; j < 4; ++j) {
            double y0 = yv[j * 4 + 0] * invn, y1 = yv[j * 4 + 1] * invn;
            double y2 = yv[j * 4 + 2] * invn, y3 = yv[j * 4 + 3] * invn;
            uint2 pk;
            pk.x = (unsigned)f2bf((float)y0) | ((unsigned)f2bf((float)y1) << 16);
            pk.y = (unsigned)f2bf((float)y2) | ((unsigned)f2bf((float)y3) << 16);
            *(uint2*)(dst + lane * 4 + j * 256) = pk;

            const float4 g1v = *(const float4*)(g1 + lane * 4 + j * 256);
            const float4 b1v = *(const float4*)(b1 + lane * 4 + j * 256);
            double w0 = y0 * (double)g1v.x, w1 = y1 * (double)g1v.y;
            double w2 = y2 * (double)g1v.z, w3 = y3 * (double)g1v.w;
            double* wp = wrow + lane * 4 + j * 256;
            double2 t0; t0.x = w0; t0.y = w1;
            double2 t1; t1.x = w2; t1.y = w3;
            *(double2*)(wp) = t0;
            *(double2*)(wp + 2) = t1;
            c1 += ((double)b1v.x * y0 + (double)b1v.y * y1) +
                  ((double)b1v.z * y2 + (double)b1v.w * y3);
            c2 += (w0 + w1) + (w2 + w3);
        }
        c1 = wave_reduce_sum_d(c1);
        c2 = wave_reduce_sum_d(c2);
        if (lane == 0) {
            consts[(size_t)q * 2 + 0] = c1;
            consts[(size_t)q * 2 + 1] = c2;
        }
    }
}

// ---------------------------------------------------------------------------
// Kernel 2: candidate GEMM, 256x256 tile, 8 waves (2Mx4N), BK=32,
// double-buffered LDS with 1-tile-ahead prefetch and COUNTED vmcnt across
// raw s_barriers (loads never drained to 0 inside the loop).
// Per iter: ds_read frags(t) -> lgkmcnt(0) -> barrier -> stage(t+2) ->
//           32 MFMA -> vmcnt(4) [t+1 resident, t+2 in flight] -> barrier.
// ---------------------------------------------------------------------------
#define BM2 256
#define BN2 256
#define BK2 32
#define NT2 (DIMN / BK2)

__global__ __launch_bounds__(512) void sim_gemm(
    const __hip_bfloat16* __restrict__ x2n, const __hip_bfloat16* __restrict__ x1n,
    ushort_t* __restrict__ simkey) {
    __shared__ __align__(16) ushort_t As2[2][BM2][BK2];   // 2 x 16 KB
    __shared__ __align__(16) ushort_t Bs2[2][BN2][BK2];   // 2 x 16 KB

    // 256 blocks; XCD swizzle (256 % 8 == 0). Pairs (2 q-tiles of one n-tile)
    // stay on one XCD for B-panel L2 reuse.
    const int bid = blockIdx.x;
    const int l = (bid & 7) * 32 + (bid >> 3);
    const int q0 = (l & 1) * BM2;
    const int n0 = (l >> 1) * BN2;

    const int tid = threadIdx.x;
    const int ln = tid & 63, wv = tid >> 6;          // 8 waves
    const int wr = wv >> 2, wc = wv & 3;             // 2 x 4 wave grid

    const int st_r = ln >> 2;                        // 0..15 row in 16-row chunk
    const int st_c = (ln & 3) * 8;                   // 0,8,16,24 elems

    const ushort_t* Ab = (const ushort_t*)x2n;
    const ushort_t* Bb = (const ushort_t*)x1n;

    f32x4 acc[8][4];
    #pragma unroll
    for (int m = 0; m < 8; ++m)
        #pragma unroll
        for (int n = 0; n < 4; ++n) acc[m][n] = (f32x4)0.0f;

    const int lr = ln & 15;
    const int lk = (ln >> 4) * 8;

    // prologue: stage tiles 0 and 1 (4 gloads each per thread)
    #pragma unroll
    for (int tt = 0; tt < 2; ++tt) {
        const int kt = tt * BK2;
        #pragma unroll
        for (int i = 0; i < 2; ++i) {
            int c = i * 8 + wv;                       // chunk 0..15 (16 rows)
            int row = c * 16 + st_r;
            gload_lds16(Ab + (size_t)(q0 + row) * DIMN + kt + st_c,
                        (char*)&As2[tt][0][0] + c * 1024);
            gload_lds16(Bb + (size_t)(n0 + row) * DIMN + kt + st_c,
                        (char*)&Bs2[tt][0][0] + c * 1024);
        }
    }
    asm volatile("s_waitcnt vmcnt(4)" ::: "memory");   // tile 0 resident
    __builtin_amdgcn_s_barrier();

    #pragma unroll 1
    for (int t = 0; t < NT2; ++t) {
        const int cur = t & 1;

        short8 af[8], bfr[4];
        #pragma unroll
        for (int m = 0; m < 8; ++m)
            af[m] = *(const short8*)&As2[cur][wr * 128 + m * 16 + lr][lk];
        #pragma unroll
        for (int n = 0; n < 4; ++n)
            bfr[n] = *(const short8*)&Bs2[cur][wc * 64 + n * 16 + lr][lk];
        asm volatile("s_waitcnt lgkmcnt(0)" ::: "memory");  // my reads landed
        __builtin_amdgcn_s_barrier();                       // all waves done reading
        __builtin_amdgcn_sched_barrier(0);

        if (t + 2 < NT2) {                                  // stage t+2 into buf[cur]
            const int kt = (t + 2) * BK2;
            #pragma unroll
            for (int i = 0; i < 2; ++i) {
                int c = i * 8 + wv;
                int row = c * 16 + st_r;
                gload_lds16(Ab + (size_t)(q0 + row) * DIMN + kt + st_c,
                            (char*)&As2[cur][0][0] + c * 1024);
                gload_lds16(Bb + (size_t)(n0 + row) * DIMN + kt + st_c,
                            (char*)&Bs2[cur][0][0] + c * 1024);
            }
        }

        #pragma unroll
        for (int m = 0; m < 8; ++m)
            #pragma unroll
            for (int n = 0; n < 4; ++n)
                acc[m][n] = __builtin_amdgcn_mfma_f32_16x16x32_bf16(
                    af[m], bfr[n], acc[m][n], 0, 0, 0);

        if (t < NT2 - 1) {
            if (t < NT2 - 2)
                asm volatile("s_waitcnt vmcnt(4)" ::: "memory");  // t+1 resident
            else
                asm volatile("s_waitcnt vmcnt(0)" ::: "memory");
            __builtin_amdgcn_s_barrier();
        }
    }

    const int crow = (ln >> 4) * 4;
    #pragma unroll
    for (int m = 0; m < 8; ++m) {
        #pragma unroll
        for (int n = 0; n < 4; ++n) {
            int col = n0 + wc * 64 + n * 16 + lr;
            #pragma unroll
            for (int r = 0; r < 4; ++r) {
                int row = q0 + wr * 128 + m * 16 + crow + r;
                simkey[(size_t)row * N1C + col] =
                    (ushort_t)key_of_bf16((unsigned)f2bf(acc[m][n][r]));
            }
        }
    }
}

// ---------------------------------------------------------------------------
// Kernel 3a: per-(q, segment) top->=MCAND via 2-pass RADIX-SELECT (R14).
// ---------------------------------------------------------------------------
__global__ __launch_bounds__(256) void seg_topk_rad(
    const ushort_t* __restrict__ simkey, unsigned* __restrict__ segcand,
    int* __restrict__ segcnt) {
    const int bid = blockIdx.x;
    const int seg = bid & 3, q = bid >> 2;
    const int tid = threadIdx.x;
    const int lane = tid & 63, wave = tid >> 6;

    __shared__ unsigned histA[256], histB[256];
    __shared__ unsigned scnt;
    __shared__ unsigned hb_sh, above_sh, lb_sh, dummy_sh;

    histA[tid] = 0;
    histB[tid] = 0;
    if (tid == 0) scnt = 0;

    const unsigned* rowPair =
        (const unsigned*)(simkey + (size_t)q * N1C) + seg * (SEG / 2);
    unsigned kreg[16];
    #pragma unroll
    for (int s = 0; s < 16; ++s)
        kreg[s] = rowPair[s * 256 + tid];
    __syncthreads();

    #pragma unroll
    for (int s = 0; s < 16; ++s) {
        atomicAdd(&histA[(kreg[s] >> 8) & 0xFFu], 1u);
        atomicAdd(&histA[kreg[s] >> 24], 1u);
    }
    __syncthreads();
    if (wave == 0) radix_scan_w0(histA, MCAND, lane, &hb_sh, &above_sh);
    __syncthreads();
    const unsigned hb = hb_sh;
    const unsigned need2 = MCAND - above_sh;

    #pragma unroll
    for (int s = 0; s < 16; ++s) {
        unsigned k0 = kreg[s] & 0xFFFFu, k1 = kreg[s] >> 16;
        if ((k0 >> 8) == hb) atomicAdd(&histB[k0 & 0xFFu], 1u);
        if ((k1 >> 8) == hb) atomicAdd(&histB[k1 & 0xFFu], 1u);
    }
    __syncthreads();
    if (wave == 0) radix_scan_w0(histB, need2, lane, &lb_sh, &dummy_sh);
    __syncthreads();
    const unsigned thr = (hb << 8) | lb_sh;

    #pragma unroll
    for (int s = 0; s < 16; ++s) {
        unsigned k0 = kreg[s] & 0xFFFFu, k1 = kreg[s] >> 16;
        unsigned e0 = (unsigned)(seg * SEG + (s * 256 + tid) * 2);
        if (k0 >= thr) {
            unsigned p = atomicAdd(&scnt, 1u);
            if (p < SEGCAP) segcand[(size_t)bid * SEGCAP + p] = (k0 << 16) | e0;
        }
        if (k1 >= thr) {
            unsigned p = atomicAdd(&scnt, 1u);
            if (p < SEGCAP) segcand[(size_t)bid * SEGCAP + p] = (k1 << 16) | (e0 + 1);
        }
    }
    __syncthreads();
    if (tid == 0) segcnt[bid] = (int)(scnt < SEGCAP ? scnt : SEGCAP);
}

// ---------------------------------------------------------------------------
// Kernel 3b: merge 4 segments' pools via the same 2-pass radix-select (R14).
// ---------------------------------------------------------------------------
__global__ __launch_bounds__(256) void merge_cand(
    const unsigned* __restrict__ segcand, const int* __restrict__ segcnt,
    int* __restrict__ cand, int* __restrict__ cand_cnt) {
    const int q = blockIdx.x;
    const int tid = threadIdx.x;
    const int lane = tid & 63, wave = tid >> 6;

    __shared__ unsigned buf[4 * SEGCAP];
    __shared__ int offs[5];
    __shared__ unsigned histA[256], histB[256];
    __shared__ unsigned cnt;
    __shared__ unsigned hb_sh, above_sh, lb_sh, dummy_sh;

    histA[tid] = 0;
    histB[tid] = 0;
    if (tid == 0) {
        int o = 0;
        #pragma unroll
        for (int s = 0; s < 4; ++s) { offs[s] = o; o += segcnt[q * 4 + s]; }
        offs[4] = o;
        cnt = 0;
    }
    __syncthreads();
    const int tot = offs[4];
    #pragma unroll
    for (int s = 0; s < 4; ++s) {
        int cs = offs[s + 1] - offs[s];
        for (int i = tid; i < cs; i += 256)
            buf[offs[s] + i] = segcand[(size_t)(q * 4 + s) * SEGCAP + i];
    }
    __syncthreads();

    unsigned e0 = 0, e1 = 0, e2 = 0, e3 = 0;
    const bool h0 = tid < tot, h1 = tid + 256 < tot,
               h2 = tid + 512 < tot, h3 = tid + 768 < tot;
    if (h0) e0 = buf[tid];
    if (h1) e1 = buf[tid + 256];
    if (h2) e2 = buf[tid + 512];
    if (h3) e3 = buf[tid + 768];

    if (h0) atomicAdd(&histA[e0 >> 24], 1u);
    if (h1) atomicAdd(&histA[e1 >> 24], 1u);
    if (h2) atomicAdd(&histA[e2 >> 24], 1u);
    if (h3) atomicAdd(&histA[e3 >> 24], 1u);
    __syncthreads();
    if (wave == 0) radix_scan_w0(histA, MCAND, lane, &hb_sh, &above_sh);
    __syncthreads();
    const unsigned hb = hb_sh;
    const unsigned need2 = MCAND - above_sh;

    if (h0 && (e0 >> 24) == hb) atomicAdd(&histB[(e0 >> 16) & 0xFFu], 1u);
    if (h1 && (e1 >> 24) == hb) atomicAdd(&histB[(e1 >> 16) & 0xFFu], 1u);
    if (h2 && (e2 >> 24) == hb) atomicAdd(&histB[(e2 >> 16) & 0xFFu], 1u);
    if (h3 && (e3 >> 24) == hb) atomicAdd(&histB[(e3 >> 16) & 0xFFu], 1u);
    __syncthreads();
    if (wave == 0) radix_scan_w0(histB, need2, lane, &lb_sh, &dummy_sh);
    __syncthreads();
    const unsigned thr = (hb << 8) | lb_sh;

    if (h0 && (e0 >> 16) >= thr) {
        unsigned p = atomicAdd(&cnt, 1u);
        if (p < CAP) cand[(size_t)q * CAP + p] = (int)(e0 & 0xFFFFu);
    }
    if (h1 && (e1 >> 16) >= thr) {
        unsigned p = atomicAdd(&cnt, 1u);
        if (p < CAP) cand[(size_t)q * CAP + p] = (int)(e1 & 0xFFFFu);
    }
    if (h2 && (e2 >> 16) >= thr) {
        unsigned p = atomicAdd(&cnt, 1u);
        if (p < CAP) cand[(size_t)q * CAP + p] = (int)(e2 & 0xFFFFu);
    }
    if (h3 && (e3 >> 16) >= thr) {
        unsigned p = atomicAdd(&cnt, 1u);
        if (p < CAP) cand[(size_t)q * CAP + p] = (int)(e3 & 0xFFFFu);
    }
    __syncthreads();
    if (tid == 0) cand_cnt[q] = (int)(cnt < CAP ? cnt : CAP);
}

// ---------------------------------------------------------------------------
// Kernel 4a: fp64 factorized scoring, 4 candidates in flight per wave.
// ---------------------------------------------------------------------------
__global__ __launch_bounds__(256) void score_cand(
    const float* __restrict__ x1, const double* __restrict__ stats1,
    const double* __restrict__ wq, const double* __restrict__ consts,
    const int* __restrict__ cand, const int* __restrict__ cand_cnt,
    double* __restrict__ vals) {
    const int q = blockIdx.x, chunk = blockIdx.y;
    const int tid = threadIdx.x;
    const int lane = tid & 63, wv = tid >> 6;
    const int cnt = cand_cnt[q];
    const int cbase = chunk * 16;
    if (cbase >= cnt) return;

    const double C1 = consts[(size_t)q * 2 + 0];
    const double C2 = consts[(size_t)q * 2 + 1];

    const double* w = wq + (size_t)q * DIMN;
    double wr[16];
    #pragma unroll
    for (int j = 0; j < 4; ++j) {
        double2 a = *(const double2*)(w + lane * 4 + j * 256);
        double2 b = *(const double2*)(w + lane * 4 + j * 256 + 2);
        wr[j * 4 + 0] = a.x; wr[j * 4 + 1] = a.y;
        wr[j * 4 + 2] = b.x; wr[j * 4 + 3] = b.y;
    }

    const int cA = cbase + wv;
    const int cB = cA + 4;
    const int cC = cA + 8;
    const int cD = cA + 12;
    const bool hA = cA < cnt, hB = cB < cnt, hC = cC < cnt, hD = cD < cnt;
    if (!hA) return;
    const int nA = cand[(size_t)q * CAP + cA];
    const int nB = hB ? cand[(size_t)q * CAP + cB] : nA;
    const int nC = hC ? cand[(size_t)q * CAP + cC] : nA;
    const int nD = hD ? cand[(size_t)q * CAP + cD] : nA;
    const float* xrA = x1 + (size_t)nA * DIMN;
    const float* xrB = x1 + (size_t)nB * DIMN;
    const float* xrC = x1 + (size_t)nC * DIMN;
    const float* xrD = x1 + (size_t)nD * DIMN;

    double aA = 0.0, aB = 0.0, aC = 0.0, aD = 0.0;
    #pragma unroll
    for (int j = 0; j < 4; ++j) {
        float4 xa = *(const float4*)(xrA + lane * 4 + j * 256);
        float4 xb = *(const float4*)(xrB + lane * 4 + j * 256);
        float4 xc = *(const float4*)(xrC + lane * 4 + j * 256);
        float4 xd = *(const float4*)(xrD + lane * 4 + j * 256);
        aA += (double)xa.x * wr[j * 4 + 0] + (double)xa.y * wr[j * 4 + 1] +
              (double)xa.z * wr[j * 4 + 2] + (double)xa.w * wr[j * 4 + 3];
        aB += (double)xb.x * wr[j * 4 + 0] + (double)xb.y * wr[j * 4 + 1] +
              (double)xb.z * wr[j * 4 + 2] + (double)xb.w * wr[j * 4 + 3];
        aC += (double)xc.x * wr[j * 4 + 0] + (double)xc.y * wr[j * 4 + 1] +
              (double)xc.z * wr[j * 4 + 2] + (double)xc.w * wr[j * 4 + 3];
        aD += (double)xd.x * wr[j * 4 + 0] + (double)xd.y * wr[j * 4 + 1] +
              (double)xd.z * wr[j * 4 + 2] + (double)xd.w * wr[j * 4 + 3];
    }
    aA = wave_reduce_sum_d(aA);
    aB = wave_reduce_sum_d(aB);
    aC = wave_reduce_sum_d(aC);
    aD = wave_reduce_sum_d(aD);
    if (lane == 0) {
        {
            const double mu1 = stats1[(size_t)nA * 3 + 0];
            const double rstd1 = stats1[(size_t)nA * 3 + 1];
            const double invn1 = stats1[(size_t)nA * 3 + 2];
            vals[(size_t)q * CAP + cA] = (rstd1 * invn1) * (aA - mu1 * C2) + invn1 * C1;
        }
        if (hB) {
            const double mu1 = stats1[(size_t)nB * 3 + 0];
            const double rstd1 = stats1[(size_t)nB * 3 + 1];
            const double invn1 = stats1[(size_t)nB * 3 + 2];
            vals[(size_t)q * CAP + cB] = (rstd1 * invn1) * (aB - mu1 * C2) + invn1 * C1;
        }
        if (hC) {
            const double mu1 = stats1[(size_t)nC * 3 + 0];
            const double rstd1 = stats1[(size_t)nC * 3 + 1];
            const double invn1 = stats1[(size_t)nC * 3 + 2];
            vals[(size_t)q * CAP + cC] = (rstd1 * invn1) * (aC - mu1 * C2) + invn1 * C1;
        }
        if (hD) {
            const double mu1 = stats1[(size_t)nD * 3 + 0];
            const double rstd1 = stats1[(size_t)nD * 3 + 1];
            const double invn1 = stats1[(size_t)nD * 3 + 2];
            vals[(size_t)q * CAP + cD] = (rstd1 * invn1) * (aD - mu1 * C2) + invn1 * C1;
        }
    }
}

// ---------------------------------------------------------------------------
// Kernel 4b: exact top-64 selection (value desc, idx asc). One wave per q.
// ---------------------------------------------------------------------------
__global__ __launch_bounds__(64) void select_topk(
    const double* __restrict__ vals, const int* __restrict__ cand,
    const int* __restrict__ cand_cnt, float* __restrict__ out) {
    const int q = blockIdx.x;
    const int lane = threadIdx.x;
    const int cnt = cand_cnt[q];

    double v0 = (lane < cnt)       ? vals[(size_t)q * CAP + lane]       : -1e300;
    double v1 = (lane + 64 < cnt)  ? vals[(size_t)q * CAP + lane + 64]  : -1e300;
    double v2 = (lane + 128 < cnt) ? vals[(size_t)q * CAP + lane + 128] : -1e300;
    double v3 = (lane + 192 < cnt) ? vals[(size_t)q * CAP + lane + 192] : -1e300;
    int i0 = (lane < cnt)       ? cand[(size_t)q * CAP + lane]       : 0x7FFFFFFF;
    int i1 = (lane + 64 < cnt)  ? cand[(size_t)q * CAP + lane + 64]  : 0x7FFFFFFF;
    int i2 = (lane + 128 < cnt) ? cand[(size_t)q * CAP + lane + 128] : 0x7FFFFFFF;
    int i3 = (lane + 192 < cnt) ? cand[(size_t)q * CAP + lane + 192] : 0x7FFFFFFF;

    for (int k = 0; k < KTOP; ++k) {
        bool a01 = (v0 > v1) || (v0 == v1 && i0 < i1);
        double va = a01 ? v0 : v1; int ia = a01 ? i0 : i1; int sa = a01 ? 0 : 1;
        bool a23 = (v2 > v3) || (v2 == v3 && i2 < i3);
        double vb = a23 ? v2 : v3; int ib = a23 ? i2 : i3; int sb = a23 ? 2 : 3;
        bool ab = (va > vb) || (va == vb && ia < ib);
        double mv = ab ? va : vb; int mi = ab ? ia : ib; int slot = ab ? sa : sb;
        int owner = lane;
        #pragma unroll
        for (int off = 32; off > 0; off >>= 1) {
            double ov = __shfl_down(mv, off, 64);
            int oi = __shfl_down(mi, off, 64);
            int oo = __shfl_down(owner, off, 64);
            int os = __shfl_down(slot, off, 64);
            bool take = (ov > mv) || (ov == mv && oi < mi);
            if (take) { mv = ov; mi = oi; owner = oo; slot = os; }
        }
        int wown = __shfl(owner, 0, 64);
        int wslot = __shfl(slot, 0, 64);
        int wmi = __shfl(mi, 0, 64);
        if (lane == 0) out[(size_t)q * KTOP + k] = (float)wmi * (1.0f / 32768.0f);
        if (lane == wown) {
            v0 = (wslot == 0) ? -1e300 : v0;
            v1 = (wslot == 1) ? -1e300 : v1;
            v2 = (wslot == 2) ? -1e300 : v2;
            v3 = (wslot == 3) ? -1e300 : v3;
        }
    }
}

// ---------------------------------------------------------------------------
extern "C" void kernel_launch(void* const* d_in, const int* in_sizes, int n_in,
                              void* d_out, int out_size, void* d_ws, size_t ws_size,
                              hipStream_t stream) {
    const float* prior = (const float*)d_in[0];
    const float* clip  = (const float*)d_in[1];
    const float* g1    = (const float*)d_in[2];
    const float* b1    = (const float*)d_in[3];
    const float* g2    = (const float*)d_in[4];
    const float* b2    = (const float*)d_in[5];
    float* out = (float*)d_out;

    char* ws = (char*)d_ws;
    size_t off = 0;
    double* stats1 = (double*)(ws + off); off += (size_t)N1C * 3 * sizeof(double);
    __hip_bfloat16* x1n = (__hip_bfloat16*)(ws + off); off += (size_t)N1C * DIMN * 2;
    __hip_bfloat16* x2n = (__hip_bfloat16*)(ws + off); off += (size_t)N2C * DIMN * 2;
    ushort_t* simkey = (ushort_t*)(ws + off); off += (size_t)N2C * N1C * 2;
    unsigned* segcand = (unsigned*)(ws + off); off += (size_t)N2C * 4 * SEGCAP * 4;
    int* segcnt = (int*)(ws + off); off += (size_t)N2C * 4 * sizeof(int);
    int* cand = (int*)(ws + off); off += (size_t)N2C * CAP * sizeof(int);
    int* cand_cnt = (int*)(ws + off); off += (size_t)N2C * sizeof(int);
    double* wq = (double*)(ws + off); off += (size_t)N2C * DIMN * sizeof(double);
    double* consts = (double*)(ws + off); off += (size_t)N2C * 2 * sizeof(double);
    double* vals = (double*)(ws + off); off += (size_t)N2C * CAP * sizeof(double);

    ln_all<<<N1C / 4 + N2C / 4, 256, 0, stream>>>(
        prior, clip, g1, b1, g2, b2, x1n, x2n, stats1, wq, consts);

    sim_gemm<<<(N1C / BN2) * (N2C / BM2), 512, 0, stream>>>(x2n, x1n, simkey);

    seg_topk_rad<<<N2C * 4, 256, 0, stream>>>(simkey, segcand, segcnt);
    merge_cand<<<N2C, 256, 0, stream>>>(segcand, segcnt, cand, cand_cnt);

    dim3 gs(N2C, 16);
    score_cand<<<gs, 256, 0, stream>>>(prior, stats1, wq, consts, cand, cand_cnt, vals);
    select_topk<<<N2C, 64, 0, stream>>>(vals, cand, cand_cnt, out);
}

// Round 16
// 183.108 us; speedup vs baseline: 1.4635x; 1.0303x over previous
//
#include <hip/hip_runtime.h>
#include <hip/hip_bf16.h>
#include <stdint.h>

#define DIMN 1024
#define N1C 32768
#define N2C 512
#define KTOP 64
#define MCAND 80
#define CAP 256
#define SEG 8192
#define SEGCAP 256

typedef unsigned short ushort_t;
typedef __attribute__((ext_vector_type(8))) short short8;
typedef __attribute__((ext_vector_type(4))) float f32x4;

__device__ __forceinline__ double wave_reduce_sum_d(double v) {
    #pragma unroll
    for (int off = 32; off > 0; off >>= 1)
        v += __shfl_down(v, off, 64);
    return v;
}

__device__ __forceinline__ void gload_lds16(const void* g, void* l) {
    __builtin_amdgcn_global_load_lds(
        (const __attribute__((address_space(1))) unsigned*)g,
        (__attribute__((address_space(3))) unsigned*)l, 16, 0, 0);
}

__device__ __forceinline__ ushort_t f2bf(float f) {
    __hip_bfloat16 h = __float2bfloat16(f);
    return *reinterpret_cast<ushort_t*>(&h);
}

__device__ __forceinline__ unsigned key_of_bf16(unsigned u16) {
    return (u16 & 0x8000u) ? (0xFFFFu & ~u16) : (u16 | 0x8000u);
}

// Wave-0 radix scan over a 256-bin LDS histogram (see R14).
__device__ __forceinline__ void radix_scan_w0(
    const unsigned* hist, unsigned need, int lane,
    unsigned* out_b, unsigned* out_above) {
    unsigned p0 = hist[lane * 4 + 0], p1 = hist[lane * 4 + 1];
    unsigned p2 = hist[lane * 4 + 2], p3 = hist[lane * 4 + 3];
    unsigned suf = p0 + p1 + p2 + p3;
    #pragma unroll
    for (int off = 1; off < 64; off <<= 1) {
        unsigned o = __shfl_down(suf, off, 64);
        if (lane + off < 64) suf += o;
    }
    unsigned next = __shfl_down(suf, 1, 64);
    if (lane == 63) next = 0u;
    unsigned s3 = next + p3;
    unsigned s2 = s3 + p2;
    unsigned s1 = s2 + p1;
    unsigned s0 = s1 + p0;
    if (s3 >= need && next < need) { *out_b = (unsigned)(lane * 4 + 3); *out_above = next; }
    if (s2 >= need && s3 < need)   { *out_b = (unsigned)(lane * 4 + 2); *out_above = s3; }
    if (s1 >= need && s2 < need)   { *out_b = (unsigned)(lane * 4 + 1); *out_above = s2; }
    if (s0 >= need && s1 < need)   { *out_b = (unsigned)(lane * 4 + 0); *out_above = s1; }
}

// ---------------------------------------------------------------------------
// Kernel 1: fused LN for BOTH inputs, wave-per-row, barrier-free.
// ---------------------------------------------------------------------------
__global__ __launch_bounds__(256) void ln_all(
    const float* __restrict__ prior, const float* __restrict__ clip,
    const float* __restrict__ g1, const float* __restrict__ b1,
    const float* __restrict__ g2, const float* __restrict__ b2,
    __hip_bfloat16* __restrict__ x1n, __hip_bfloat16* __restrict__ x2n,
    double* __restrict__ stats1, double* __restrict__ wq,
    double* __restrict__ consts) {
    const int bid = blockIdx.x;
    const int tid = threadIdx.x;
    const int lane = tid & 63, wave = tid >> 6;

    if (bid < N1C / 4) {
        const int row = bid * 4 + wave;
        const float* xr = prior + (size_t)row * DIMN;
        float4 xv[4], gv[4], bv[4];
        #pragma unroll
        for (int j = 0; j < 4; ++j) {
            xv[j] = *(const float4*)(xr + lane * 4 + j * 256);
            gv[j] = *(const float4*)(g1 + lane * 4 + j * 256);
            bv[j] = *(const float4*)(b1 + lane * 4 + j * 256);
        }
        double s = 0.0, s2 = 0.0;
        #pragma unroll
        for (int j = 0; j < 4; ++j) {
            double a = xv[j].x, b = xv[j].y, c = xv[j].z, d = xv[j].w;
            s += (a + b) + (c + d);
            s2 += (a * a + b * b) + (c * c + d * d);
        }
        s = wave_reduce_sum_d(s);
        s2 = wave_reduce_sum_d(s2);
        double mu, rstd;
        if (lane == 0) {
            mu = s / (double)DIMN;
            double var = s2 / (double)DIMN - mu * mu;
            rstd = 1.0 / sqrt(var + 1e-5);
        }
        mu = __shfl(mu, 0, 64);
        rstd = __shfl(rstd, 0, 64);

        double y[16];
        double q = 0.0;
        #pragma unroll
        for (int j = 0; j < 4; ++j) {
            double y0 = ((double)xv[j].x - mu) * rstd * (double)gv[j].x + (double)bv[j].x;
            double y1 = ((double)xv[j].y - mu) * rstd * (double)gv[j].y + (double)bv[j].y;
            double y2 = ((double)xv[j].z - mu) * rstd * (double)gv[j].z + (double)bv[j].z;
            double y3 = ((double)xv[j].w - mu) * rstd * (double)gv[j].w + (double)bv[j].w;
            y[j * 4 + 0] = y0; y[j * 4 + 1] = y1; y[j * 4 + 2] = y2; y[j * 4 + 3] = y3;
            q += (y0 * y0 + y1 * y1) + (y2 * y2 + y3 * y3);
        }
        q = wave_reduce_sum_d(q);
        double invn;
        if (lane == 0) {
            invn = 1.0 / fmax(sqrt(q), 1e-8);
            stats1[(size_t)row * 3 + 0] = mu;
            stats1[(size_t)row * 3 + 1] = rstd;
            stats1[(size_t)row * 3 + 2] = invn;
        }
        invn = __shfl(invn, 0, 64);

        ushort_t* dst = (ushort_t*)x1n + (size_t)row * DIMN;
        #pragma unroll
        for (int j = 0; j < 4; ++j) {
            uint2 pk;
            pk.x = (unsigned)f2bf((float)(y[j * 4 + 0] * invn)) |
                   ((unsigned)f2bf((float)(y[j * 4 + 1] * invn)) << 16);
            pk.y = (unsigned)f2bf((float)(y[j * 4 + 2] * invn)) |
                   ((unsigned)f2bf((float)(y[j * 4 + 3] * invn)) << 16);
            *(uint2*)(dst + lane * 4 + j * 256) = pk;
        }
    } else {
        const int q = (bid - N1C / 4) * 4 + wave;
        const float* xr = clip + (size_t)q * DIMN;
        float4 xv[4];
        #pragma unroll
        for (int j = 0; j < 4; ++j)
            xv[j] = *(const float4*)(xr + lane * 4 + j * 256);

        double s = 0.0, s2 = 0.0;
        #pragma unroll
        for (int j = 0; j < 4; ++j) {
            double a = xv[j].x, b = xv[j].y, c = xv[j].z, d = xv[j].w;
            s += (a + b) + (c + d);
            s2 += (a * a + b * b) + (c * c + d * d);
        }
        s = wave_reduce_sum_d(s);
        s2 = wave_reduce_sum_d(s2);
        double mu, rstd;
        if (lane == 0) {
            mu = s / (double)DIMN;
            double var = s2 / (double)DIMN - mu * mu;
            rstd = 1.0 / sqrt(var + 1e-5);
        }
        mu = __shfl(mu, 0, 64);
        rstd = __shfl(rstd, 0, 64);

        double yv[16];
        double qq = 0.0;
        #pragma unroll
        for (int j = 0; j < 4; ++j) {
            const float4 g2v = *(const float4*)(g2 + lane * 4 + j * 256);
            const float4 b2v = *(const float4*)(b2 + lane * 4 + j * 256);
            double y0 = ((double)xv[j].x - mu) * rstd * (double)g2v.x + (double)b2v.x;
            double y1 = ((double)xv[j].y - mu) * rstd * (double)g2v.y + (double)b2v.y;
            double y2 = ((double)xv[j].z - mu) * rstd * (double)g2v.z + (double)b2v.z;
            double y3 = ((double)xv[j].w - mu) * rstd * (double)g2v.w + (double)b2v.w;
            yv[j * 4 + 0] = y0; yv[j * 4 + 1] = y1;
            yv[j * 4 + 2] = y2; yv[j * 4 + 3] = y3;
            qq += (y0 * y0 + y1 * y1) + (y2 * y2 + y3 * y3);
        }
        qq = wave_reduce_sum_d(qq);
        double invn;
        if (lane == 0) invn = 1.0 / fmax(sqrt(qq), 1e-8);
        invn = __shfl(invn, 0, 64);

        double c1 = 0.0, c2 = 0.0;
        ushort_t* dst = (ushort_t*)x2n + (size_t)q * DIMN;
        double* wrow = wq + (size_t)q * DIMN;
        #pragma unroll
        for (int j = 0; j < 4; ++j) {
            double y0 = yv[j * 4 + 0] * invn, y1 = yv[j * 4 + 1] * invn;
            double y2 = yv[j * 4 + 2] * invn, y3 = yv[j * 4 + 3] * invn;
            uint2 pk;
            pk.x = (unsigned)f2bf((float)y0) | ((unsigned)f2bf((float)y1) << 16);
            pk.y = (unsigned)f2bf((float)y2) | ((unsigned)f2bf((float)y3) << 16);
            *(uint2*)(dst + lane * 4 + j * 256) = pk;

            const float4 g1v = *(const float4*)(g1 + lane * 4 + j * 256);
            const float4 b1v = *(const float4*)(b1 + lane * 4 + j * 256);
            double w0 = y0 * (double)g1v.x, w1 = y1 * (double)g1v.y;
            double w2 = y2 * (double)g1v.z, w3 = y3 * (double)g1v.w;
            double* wp = wrow + lane * 4 + j * 256;
            double2 t0; t0.x = w0; t0.y = w1;
            double2 t1; t1.x = w2; t1.y = w3;
            *(double2*)(wp) = t0;
            *(double2*)(wp + 2) = t1;
            c1 += ((double)b1v.x * y0 + (double)b1v.y * y1) +
                  ((double)b1v.z * y2 + (double)b1v.w * y3);
            c2 += (w0 + w1) + (w2 + w3);
        }
        c1 = wave_reduce_sum_d(c1);
        c2 = wave_reduce_sum_d(c2);
        if (lane == 0) {
            consts[(size_t)q * 2 + 0] = c1;
            consts[(size_t)q * 2 + 1] = c2;
        }
    }
}

// ---------------------------------------------------------------------------
// Kernel 2: candidate GEMM, 256x256 tile, 8 waves (2Mx4N), BK=32,
// TRIPLE-buffered LDS (96 KB): iter t reads buf[t%3], stages t+2 into
// buf[(t+2)%3] (= buf[(t-1)%3], safe: end-of-iter barrier guarantees all
// waves finished t-1 reads). ONE barrier per iter; per-wave lgkmcnt(0);
// counted vmcnt(4); setprio(1) around the MFMA cluster.
// ---------------------------------------------------------------------------
#define BM2 256
#define BN2 256
#define BK2 32
#define NT2 (DIMN / BK2)

__global__ __launch_bounds__(512) void sim_gemm(
    const __hip_bfloat16* __restrict__ x2n, const __hip_bfloat16* __restrict__ x1n,
    ushort_t* __restrict__ simkey) {
    __shared__ __align__(16) ushort_t As2[3][BM2][BK2];   // 3 x 16 KB
    __shared__ __align__(16) ushort_t Bs2[3][BN2][BK2];   // 3 x 16 KB

    const int bid = blockIdx.x;
    const int l = (bid & 7) * 32 + (bid >> 3);
    const int q0 = (l & 1) * BM2;
    const int n0 = (l >> 1) * BN2;

    const int tid = threadIdx.x;
    const int ln = tid & 63, wv = tid >> 6;
    const int wr = wv >> 2, wc = wv & 3;

    const int st_r = ln >> 2;
    const int st_c = (ln & 3) * 8;

    const ushort_t* Ab = (const ushort_t*)x2n;
    const ushort_t* Bb = (const ushort_t*)x1n;

    f32x4 acc[8][4];
    #pragma unroll
    for (int m = 0; m < 8; ++m)
        #pragma unroll
        for (int n = 0; n < 4; ++n) acc[m][n] = (f32x4)0.0f;

    const int lr = ln & 15;
    const int lk = (ln >> 4) * 8;

    // prologue: stage tiles 0 and 1 into buffers 0 and 1
    #pragma unroll
    for (int tt = 0; tt < 2; ++tt) {
        const int kt = tt * BK2;
        #pragma unroll
        for (int i = 0; i < 2; ++i) {
            int c = i * 8 + wv;
            int row = c * 16 + st_r;
            gload_lds16(Ab + (size_t)(q0 + row) * DIMN + kt + st_c,
                        (char*)&As2[tt][0][0] + c * 1024);
            gload_lds16(Bb + (size_t)(n0 + row) * DIMN + kt + st_c,
                        (char*)&Bs2[tt][0][0] + c * 1024);
        }
    }
    asm volatile("s_waitcnt vmcnt(4)" ::: "memory");   // tile 0 resident
    __builtin_amdgcn_s_barrier();

    int cur = 0;
    #pragma unroll 1
    for (int t = 0; t < NT2; ++t) {
        short8 af[8], bfr[4];
        #pragma unroll
        for (int m = 0; m < 8; ++m)
            af[m] = *(const short8*)&As2[cur][wr * 128 + m * 16 + lr][lk];
        #pragma unroll
        for (int n = 0; n < 4; ++n)
            bfr[n] = *(const short8*)&Bs2[cur][wc * 64 + n * 16 + lr][lk];
        asm volatile("s_waitcnt lgkmcnt(0)" ::: "memory");  // own reads landed
        __builtin_amdgcn_sched_barrier(0);

        if (t + 2 < NT2) {                 // stage t+2 into buf[(cur+2)%3]
            int stb = cur + 2; if (stb >= 3) stb -= 3;
            const int kt = (t + 2) * BK2;
            #pragma unroll
            for (int i = 0; i < 2; ++i) {
                int c = i * 8 + wv;
                int row = c * 16 + st_r;
                gload_lds16(Ab + (size_t)(q0 + row) * DIMN + kt + st_c,
                            (char*)&As2[stb][0][0] + c * 1024);
                gload_lds16(Bb + (size_t)(n0 + row) * DIMN + kt + st_c,
                            (char*)&Bs2[stb][0][0] + c * 1024);
            }
        }

        __builtin_amdgcn_s_setprio(1);
        #pragma unroll
        for (int m = 0; m < 8; ++m)
            #pragma unroll
            for (int n = 0; n < 4; ++n)
                acc[m][n] = __builtin_amdgcn_mfma_f32_16x16x32_bf16(
                    af[m], bfr[n], acc[m][n], 0, 0, 0);
        __builtin_amdgcn_s_setprio(0);

        if (t < NT2 - 1) {
            if (t < NT2 - 2)
                asm volatile("s_waitcnt vmcnt(4)" ::: "memory");  // t+1 resident
            else
                asm volatile("s_waitcnt vmcnt(0)" ::: "memory");
            __builtin_amdgcn_s_barrier();
        }
        cur = cur + 1; if (cur >= 3) cur -= 3;
    }

    const int crow = (ln >> 4) * 4;
    #pragma unroll
    for (int m = 0; m < 8; ++m) {
        #pragma unroll
        for (int n = 0; n < 4; ++n) {
            int col = n0 + wc * 64 + n * 16 + lr;
            #pragma unroll
            for (int r = 0; r < 4; ++r) {
                int row = q0 + wr * 128 + m * 16 + crow + r;
                simkey[(size_t)row * N1C + col] =
                    (ushort_t)key_of_bf16((unsigned)f2bf(acc[m][n][r]));
            }
        }
    }
}

// ---------------------------------------------------------------------------
// Kernel 3a: per-(q, segment) top->=MCAND via 2-pass RADIX-SELECT (R14).
// ---------------------------------------------------------------------------
__global__ __launch_bounds__(256) void seg_topk_rad(
    const ushort_t* __restrict__ simkey, unsigned* __restrict__ segcand,
    int* __restrict__ segcnt) {
    const int bid = blockIdx.x;
    const int seg = bid & 3, q = bid >> 2;
    const int tid = threadIdx.x;
    const int lane = tid & 63, wave = tid >> 6;

    __shared__ unsigned histA[256], histB[256];
    __shared__ unsigned scnt;
    __shared__ unsigned hb_sh, above_sh, lb_sh, dummy_sh;

    histA[tid] = 0;
    histB[tid] = 0;
    if (tid == 0) scnt = 0;

    const unsigned* rowPair =
        (const unsigned*)(simkey + (size_t)q * N1C) + seg * (SEG / 2);
    unsigned kreg[16];
    #pragma unroll
    for (int s = 0; s < 16; ++s)
        kreg[s] = rowPair[s * 256 + tid];
    __syncthreads();

    #pragma unroll
    for (int s = 0; s < 16; ++s) {
        atomicAdd(&histA[(kreg[s] >> 8) & 0xFFu], 1u);
        atomicAdd(&histA[kreg[s] >> 24], 1u);
    }
    __syncthreads();
    if (wave == 0) radix_scan_w0(histA, MCAND, lane, &hb_sh, &above_sh);
    __syncthreads();
    const unsigned hb = hb_sh;
    const unsigned need2 = MCAND - above_sh;

    #pragma unroll
    for (int s = 0; s < 16; ++s) {
        unsigned k0 = kreg[s] & 0xFFFFu, k1 = kreg[s] >> 16;
        if ((k0 >> 8) == hb) atomicAdd(&histB[k0 & 0xFFu], 1u);
        if ((k1 >> 8) == hb) atomicAdd(&histB[k1 & 0xFFu], 1u);
    }
    __syncthreads();
    if (wave == 0) radix_scan_w0(histB, need2, lane, &lb_sh, &dummy_sh);
    __syncthreads();
    const unsigned thr = (hb << 8) | lb_sh;

    #pragma unroll
    for (int s = 0; s < 16; ++s) {
        unsigned k0 = kreg[s] & 0xFFFFu, k1 = kreg[s] >> 16;
        unsigned e0 = (unsigned)(seg * SEG + (s * 256 + tid) * 2);
        if (k0 >= thr) {
            unsigned p = atomicAdd(&scnt, 1u);
            if (p < SEGCAP) segcand[(size_t)bid * SEGCAP + p] = (k0 << 16) | e0;
        }
        if (k1 >= thr) {
            unsigned p = atomicAdd(&scnt, 1u);
            if (p < SEGCAP) segcand[(size_t)bid * SEGCAP + p] = (k1 << 16) | (e0 + 1);
        }
    }
    __syncthreads();
    if (tid == 0) segcnt[bid] = (int)(scnt < SEGCAP ? scnt : SEGCAP);
}

// ---------------------------------------------------------------------------
// Kernel 3b: merge 4 segments' pools via the same 2-pass radix-select (R14).
// ---------------------------------------------------------------------------
__global__ __launch_bounds__(256) void merge_cand(
    const unsigned* __restrict__ segcand, const int* __restrict__ segcnt,
    int* __restrict__ cand, int* __restrict__ cand_cnt) {
    const int q = blockIdx.x;
    const int tid = threadIdx.x;
    const int lane = tid & 63, wave = tid >> 6;

    __shared__ unsigned buf[4 * SEGCAP];
    __shared__ int offs[5];
    __shared__ unsigned histA[256], histB[256];
    __shared__ unsigned cnt;
    __shared__ unsigned hb_sh, above_sh, lb_sh, dummy_sh;

    histA[tid] = 0;
    histB[tid] = 0;
    if (tid == 0) {
        int o = 0;
        #pragma unroll
        for (int s = 0; s < 4; ++s) { offs[s] = o; o += segcnt[q * 4 + s]; }
        offs[4] = o;
        cnt = 0;
    }
    __syncthreads();
    const int tot = offs[4];
    #pragma unroll
    for (int s = 0; s < 4; ++s) {
        int cs = offs[s + 1] - offs[s];
        for (int i = tid; i < cs; i += 256)
            buf[offs[s] + i] = segcand[(size_t)(q * 4 + s) * SEGCAP + i];
    }
    __syncthreads();

    unsigned e0 = 0, e1 = 0, e2 = 0, e3 = 0;
    const bool h0 = tid < tot, h1 = tid + 256 < tot,
               h2 = tid + 512 < tot, h3 = tid + 768 < tot;
    if (h0) e0 = buf[tid];
    if (h1) e1 = buf[tid + 256];
    if (h2) e2 = buf[tid + 512];
    if (h3) e3 = buf[tid + 768];

    if (h0) atomicAdd(&histA[e0 >> 24], 1u);
    if (h1) atomicAdd(&histA[e1 >> 24], 1u);
    if (h2) atomicAdd(&histA[e2 >> 24], 1u);
    if (h3) atomicAdd(&histA[e3 >> 24], 1u);
    __syncthreads();
    if (wave == 0) radix_scan_w0(histA, MCAND, lane, &hb_sh, &above_sh);
    __syncthreads();
    const unsigned hb = hb_sh;
    const unsigned need2 = MCAND - above_sh;

    if (h0 && (e0 >> 24) == hb) atomicAdd(&histB[(e0 >> 16) & 0xFFu], 1u);
    if (h1 && (e1 >> 24) == hb) atomicAdd(&histB[(e1 >> 16) & 0xFFu], 1u);
    if (h2 && (e2 >> 24) == hb) atomicAdd(&histB[(e2 >> 16) & 0xFFu], 1u);
    if (h3 && (e3 >> 24) == hb) atomicAdd(&histB[(e3 >> 16) & 0xFFu], 1u);
    __syncthreads();
    if (wave == 0) radix_scan_w0(histB, need2, lane, &lb_sh, &dummy_sh);
    __syncthreads();
    const unsigned thr = (hb << 8) | lb_sh;

    if (h0 && (e0 >> 16) >= thr) {
        unsigned p = atomicAdd(&cnt, 1u);
        if (p < CAP) cand[(size_t)q * CAP + p] = (int)(e0 & 0xFFFFu);
    }
    if (h1 && (e1 >> 16) >= thr) {
        unsigned p = atomicAdd(&cnt, 1u);
        if (p < CAP) cand[(size_t)q * CAP + p] = (int)(e1 & 0xFFFFu);
    }
    if (h2 && (e2 >> 16) >= thr) {
        unsigned p = atomicAdd(&cnt, 1u);
        if (p < CAP) cand[(size_t)q * CAP + p] = (int)(e2 & 0xFFFFu);
    }
    if (h3 && (e3 >> 16) >= thr) {
        unsigned p = atomicAdd(&cnt, 1u);
        if (p < CAP) cand[(size_t)q * CAP + p] = (int)(e3 & 0xFFFFu);
    }
    __syncthreads();
    if (tid == 0) cand_cnt[q] = (int)(cnt < CAP ? cnt : CAP);
}

// ---------------------------------------------------------------------------
// Kernel 4a: fp64 factorized scoring, 4 candidates in flight per wave.
// ---------------------------------------------------------------------------
__global__ __launch_bounds__(256) void score_cand(
    const float* __restrict__ x1, const double* __restrict__ stats1,
    const double* __restrict__ wq, const double* __restrict__ consts,
    const int* __restrict__ cand, const int* __restrict__ cand_cnt,
    double* __restrict__ vals) {
    const int q = blockIdx.x, chunk = blockIdx.y;
    const int tid = threadIdx.x;
    const int lane = tid & 63, wv = tid >> 6;
    const int cnt = cand_cnt[q];
    const int cbase = chunk * 16;
    if (cbase >= cnt) return;

    const double C1 = consts[(size_t)q * 2 + 0];
    const double C2 = consts[(size_t)q * 2 + 1];

    const double* w = wq + (size_t)q * DIMN;
    double wr[16];
    #pragma unroll
    for (int j = 0; j < 4; ++j) {
        double2 a = *(const double2*)(w + lane * 4 + j * 256);
        double2 b = *(const double2*)(w + lane * 4 + j * 256 + 2);
        wr[j * 4 + 0] = a.x; wr[j * 4 + 1] = a.y;
        wr[j * 4 + 2] = b.x; wr[j * 4 + 3] = b.y;
    }

    const int cA = cbase + wv;
    const int cB = cA + 4;
    const int cC = cA + 8;
    const int cD = cA + 12;
    const bool hA = cA < cnt, hB = cB < cnt, hC = cC < cnt, hD = cD < cnt;
    if (!hA) return;
    const int nA = cand[(size_t)q * CAP + cA];
    const int nB = hB ? cand[(size_t)q * CAP + cB] : nA;
    const int nC = hC ? cand[(size_t)q * CAP + cC] : nA;
    const int nD = hD ? cand[(size_t)q * CAP + cD] : nA;
    const float* xrA = x1 + (size_t)nA * DIMN;
    const float* xrB = x1 + (size_t)nB * DIMN;
    const float* xrC = x1 + (size_t)nC * DIMN;
    const float* xrD = x1 + (size_t)nD * DIMN;

    double aA = 0.0, aB = 0.0, aC = 0.0, aD = 0.0;
    #pragma unroll
    for (int j = 0; j < 4; ++j) {
        float4 xa = *(const float4*)(xrA + lane * 4 + j * 256);
        float4 xb = *(const float4*)(xrB + lane * 4 + j * 256);
        float4 xc = *(const float4*)(xrC + lane * 4 + j * 256);
        float4 xd = *(const float4*)(xrD + lane * 4 + j * 256);
        aA += (double)xa.x * wr[j * 4 + 0] + (double)xa.y * wr[j * 4 + 1] +
              (double)xa.z * wr[j * 4 + 2] + (double)xa.w * wr[j * 4 + 3];
        aB += (double)xb.x * wr[j * 4 + 0] + (double)xb.y * wr[j * 4 + 1] +
              (double)xb.z * wr[j * 4 + 2] + (double)xb.w * wr[j * 4 + 3];
        aC += (double)xc.x * wr[j * 4 + 0] + (double)xc.y * wr[j * 4 + 1] +
              (double)xc.z * wr[j * 4 + 2] + (double)xc.w * wr[j * 4 + 3];
        aD += (double)xd.x * wr[j * 4 + 0] + (double)xd.y * wr[j * 4 + 1] +
              (double)xd.z * wr[j * 4 + 2] + (double)xd.w * wr[j * 4 + 3];
    }
    aA = wave_reduce_sum_d(aA);
    aB = wave_reduce_sum_d(aB);
    aC = wave_reduce_sum_d(aC);
    aD = wave_reduce_sum_d(aD);
    if (lane == 0) {
        {
            const double mu1 = stats1[(size_t)nA * 3 + 0];
            const double rstd1 = stats1[(size_t)nA * 3 + 1];
            const double invn1 = stats1[(size_t)nA * 3 + 2];
            vals[(size_t)q * CAP + cA] = (rstd1 * invn1) * (aA - mu1 * C2) + invn1 * C1;
        }
        if (hB) {
            const double mu1 = stats1[(size_t)nB * 3 + 0];
            const double rstd1 = stats1[(size_t)nB * 3 + 1];
            const double invn1 = stats1[(size_t)nB * 3 + 2];
            vals[(size_t)q * CAP + cB] = (rstd1 * invn1) * (aB - mu1 * C2) + invn1 * C1;
        }
        if (hC) {
            const double mu1 = stats1[(size_t)nC * 3 + 0];
            const double rstd1 = stats1[(size_t)nC * 3 + 1];
            const double invn1 = stats1[(size_t)nC * 3 + 2];
            vals[(size_t)q * CAP + cC] = (rstd1 * invn1) * (aC - mu1 * C2) + invn1 * C1;
        }
        if (hD) {
            const double mu1 = stats1[(size_t)nD * 3 + 0];
            const double rstd1 = stats1[(size_t)nD * 3 + 1];
            const double invn1 = stats1[(size_t)nD * 3 + 2];
            vals[(size_t)q * CAP + cD] = (rstd1 * invn1) * (aD - mu1 * C2) + invn1 * C1;
        }
    }
}

// ---------------------------------------------------------------------------
// Kernel 4b: exact top-64 selection (value desc, idx asc). One wave per q.
// ---------------------------------------------------------------------------
__global__ __launch_bounds__(64) void select_topk(
    const double* __restrict__ vals, const int* __restrict__ cand,
    const int* __restrict__ cand_cnt, float* __restrict__ out) {
    const int q = blockIdx.x;
    const int lane = threadIdx.x;
    const int cnt = cand_cnt[q];

    double v0 = (lane < cnt)       ? vals[(size_t)q * CAP + lane]       : -1e300;
    double v1 = (lane + 64 < cnt)  ? vals[(size_t)q * CAP + lane + 64]  : -1e300;
    double v2 = (lane + 128 < cnt) ? vals[(size_t)q * CAP + lane + 128] : -1e300;
    double v3 = (lane + 192 < cnt) ? vals[(size_t)q * CAP + lane + 192] : -1e300;
    int i0 = (lane < cnt)       ? cand[(size_t)q * CAP + lane]       : 0x7FFFFFFF;
    int i1 = (lane + 64 < cnt)  ? cand[(size_t)q * CAP + lane + 64]  : 0x7FFFFFFF;
    int i2 = (lane + 128 < cnt) ? cand[(size_t)q * CAP + lane + 128] : 0x7FFFFFFF;
    int i3 = (lane + 192 < cnt) ? cand[(size_t)q * CAP + lane + 192] : 0x7FFFFFFF;

    for (int k = 0; k < KTOP; ++k) {
        bool a01 = (v0 > v1) || (v0 == v1 && i0 < i1);
        double va = a01 ? v0 : v1; int ia = a01 ? i0 : i1; int sa = a01 ? 0 : 1;
        bool a23 = (v2 > v3) || (v2 == v3 && i2 < i3);
        double vb = a23 ? v2 : v3; int ib = a23 ? i2 : i3; int sb = a23 ? 2 : 3;
        bool ab = (va > vb) || (va == vb && ia < ib);
        double mv = ab ? va : vb; int mi = ab ? ia : ib; int slot = ab ? sa : sb;
        int owner = lane;
        #pragma unroll
        for (int off = 32; off > 0; off >>= 1) {
            double ov = __shfl_down(mv, off, 64);
            int oi = __shfl_down(mi, off, 64);
            int oo = __shfl_down(owner, off, 64);
            int os = __shfl_down(slot, off, 64);
            bool take = (ov > mv) || (ov == mv && oi < mi);
            if (take) { mv = ov; mi = oi; owner = oo; slot = os; }
        }
        int wown = __shfl(owner, 0, 64);
        int wslot = __shfl(slot, 0, 64);
        int wmi = __shfl(mi, 0, 64);
        if (lane == 0) out[(size_t)q * KTOP + k] = (float)wmi * (1.0f / 32768.0f);
        if (lane == wown) {
            v0 = (wslot == 0) ? -1e300 : v0;
            v1 = (wslot == 1) ? -1e300 : v1;
            v2 = (wslot == 2) ? -1e300 : v2;
            v3 = (wslot == 3) ? -1e300 : v3;
        }
    }
}

// ---------------------------------------------------------------------------
extern "C" void kernel_launch(void* const* d_in, const int* in_sizes, int n_in,
                              void* d_out, int out_size, void* d_ws, size_t ws_size,
                              hipStream_t stream) {
    const float* prior = (const float*)d_in[0];
    const float* clip  = (const float*)d_in[1];
    const float* g1    = (const float*)d_in[2];
    const float* b1    = (const float*)d_in[3];
    const float* g2    = (const float*)d_in[4];
    const float* b2    = (const float*)d_in[5];
    float* out = (float*)d_out;

    char* ws = (char*)d_ws;
    size_t off = 0;
    double* stats1 = (double*)(ws + off); off += (size_t)N1C * 3 * sizeof(double);
    __hip_bfloat16* x1n = (__hip_bfloat16*)(ws + off); off += (size_t)N1C * DIMN * 2;
    __hip_bfloat16* x2n = (__hip_bfloat16*)(ws + off); off += (size_t)N2C * DIMN * 2;
    ushort_t* simkey = (ushort_t*)(ws + off); off += (size_t)N2C * N1C * 2;
    unsigned* segcand = (unsigned*)(ws + off); off += (size_t)N2C * 4 * SEGCAP * 4;
    int* segcnt = (int*)(ws + off); off += (size_t)N2C * 4 * sizeof(int);
    int* cand = (int*)(ws + off); off += (size_t)N2C * CAP * sizeof(int);
    int* cand_cnt = (int*)(ws + off); off += (size_t)N2C * sizeof(int);
    double* wq = (double*)(ws + off); off += (size_t)N2C * DIMN * sizeof(double);
    double* consts = (double*)(ws + off); off += (size_t)N2C * 2 * sizeof(double);
    double* vals = (double*)(ws + off); off += (size_t)N2C * CAP * sizeof(double);

    ln_all<<<N1C / 4 + N2C / 4, 256, 0, stream>>>(
        prior, clip, g1, b1, g2, b2, x1n, x2n, stats1, wq, consts);

    sim_gemm<<<(N1C / BN2) * (N2C / BM2), 512, 0, stream>>>(x2n, x1n, simkey);

    seg_topk_rad<<<N2C * 4, 256, 0, stream>>>(simkey, segcand, segcnt);
    merge_cand<<<N2C, 256, 0, stream>>>(segcand, segcnt, cand, cand_cnt);

    dim3 gs(N2C, 16);
    score_cand<<<gs, 256, 0, stream>>>(prior, stats1, wq, consts, cand, cand_cnt, vals);
    select_topk<<<N2C, 64, 0, stream>>>(vals, cand, cand_cnt, out);
}

// Round 17
// 183.025 us; speedup vs baseline: 1.4641x; 1.0005x over previous
//
#include <hip/hip_runtime.h>
#include <hip/hip_bf16.h>
#include <stdint.h>

#define DIMN 1024
#define N1C 32768
#define N2C 512
#define KTOP 64
#define MCAND 80
#define CAP 256
#define SEG 8192
#define SEGCAP 256

typedef unsigned short ushort_t;
typedef __attribute__((ext_vector_type(8))) short short8;
typedef __attribute__((ext_vector_type(4))) float f32x4;

__device__ __forceinline__ double wave_reduce_sum_d(double v) {
    #pragma unroll
    for (int off = 32; off > 0; off >>= 1)
        v += __shfl_down(v, off, 64);
    return v;
}

__device__ __forceinline__ void gload_lds16(const void* g, void* l) {
    __builtin_amdgcn_global_load_lds(
        (const __attribute__((address_space(1))) unsigned*)g,
        (__attribute__((address_space(3))) unsigned*)l, 16, 0, 0);
}

__device__ __forceinline__ ushort_t f2bf(float f) {
    __hip_bfloat16 h = __float2bfloat16(f);
    return *reinterpret_cast<ushort_t*>(&h);
}

__device__ __forceinline__ unsigned key_of_bf16(unsigned u16) {
    return (u16 & 0x8000u) ? (0xFFFFu & ~u16) : (u16 | 0x8000u);
}

// Wave-0 radix scan over a 256-bin LDS histogram (see R14).
__device__ __forceinline__ void radix_scan_w0(
    const unsigned* hist, unsigned need, int lane,
    unsigned* out_b, unsigned* out_above) {
    unsigned p0 = hist[lane * 4 + 0], p1 = hist[lane * 4 + 1];
    unsigned p2 = hist[lane * 4 + 2], p3 = hist[lane * 4 + 3];
    unsigned suf = p0 + p1 + p2 + p3;
    #pragma unroll
    for (int off = 1; off < 64; off <<= 1) {
        unsigned o = __shfl_down(suf, off, 64);
        if (lane + off < 64) suf += o;
    }
    unsigned next = __shfl_down(suf, 1, 64);
    if (lane == 63) next = 0u;
    unsigned s3 = next + p3;
    unsigned s2 = s3 + p2;
    unsigned s1 = s2 + p1;
    unsigned s0 = s1 + p0;
    if (s3 >= need && next < need) { *out_b = (unsigned)(lane * 4 + 3); *out_above = next; }
    if (s2 >= need && s3 < need)   { *out_b = (unsigned)(lane * 4 + 2); *out_above = s3; }
    if (s1 >= need && s2 < need)   { *out_b = (unsigned)(lane * 4 + 1); *out_above = s2; }
    if (s0 >= need && s1 < need)   { *out_b = (unsigned)(lane * 4 + 0); *out_above = s1; }
}

// ---------------------------------------------------------------------------
// Kernel 1: fused LN for BOTH inputs, wave-per-row, barrier-free.
// ---------------------------------------------------------------------------
__global__ __launch_bounds__(256) void ln_all(
    const float* __restrict__ prior, const float* __restrict__ clip,
    const float* __restrict__ g1, const float* __restrict__ b1,
    const float* __restrict__ g2, const float* __restrict__ b2,
    __hip_bfloat16* __restrict__ x1n, __hip_bfloat16* __restrict__ x2n,
    double* __restrict__ stats1, double* __restrict__ wq,
    double* __restrict__ consts) {
    const int bid = blockIdx.x;
    const int tid = threadIdx.x;
    const int lane = tid & 63, wave = tid >> 6;

    if (bid < N1C / 4) {
        const int row = bid * 4 + wave;
        const float* xr = prior + (size_t)row * DIMN;
        float4 xv[4], gv[4], bv[4];
        #pragma unroll
        for (int j = 0; j < 4; ++j) {
            xv[j] = *(const float4*)(xr + lane * 4 + j * 256);
            gv[j] = *(const float4*)(g1 + lane * 4 + j * 256);
            bv[j] = *(const float4*)(b1 + lane * 4 + j * 256);
        }
        double s = 0.0, s2 = 0.0;
        #pragma unroll
        for (int j = 0; j < 4; ++j) {
            double a = xv[j].x, b = xv[j].y, c = xv[j].z, d = xv[j].w;
            s += (a + b) + (c + d);
            s2 += (a * a + b * b) + (c * c + d * d);
        }
        s = wave_reduce_sum_d(s);
        s2 = wave_reduce_sum_d(s2);
        double mu, rstd;
        if (lane == 0) {
            mu = s / (double)DIMN;
            double var = s2 / (double)DIMN - mu * mu;
            rstd = 1.0 / sqrt(var + 1e-5);
        }
        mu = __shfl(mu, 0, 64);
        rstd = __shfl(rstd, 0, 64);

        double y[16];
        double q = 0.0;
        #pragma unroll
        for (int j = 0; j < 4; ++j) {
            double y0 = ((double)xv[j].x - mu) * rstd * (double)gv[j].x + (double)bv[j].x;
            double y1 = ((double)xv[j].y - mu) * rstd * (double)gv[j].y + (double)bv[j].y;
            double y2 = ((double)xv[j].z - mu) * rstd * (double)gv[j].z + (double)bv[j].z;
            double y3 = ((double)xv[j].w - mu) * rstd * (double)gv[j].w + (double)bv[j].w;
            y[j * 4 + 0] = y0; y[j * 4 + 1] = y1; y[j * 4 + 2] = y2; y[j * 4 + 3] = y3;
            q += (y0 * y0 + y1 * y1) + (y2 * y2 + y3 * y3);
        }
        q = wave_reduce_sum_d(q);
        double invn;
        if (lane == 0) {
            invn = 1.0 / fmax(sqrt(q), 1e-8);
            stats1[(size_t)row * 3 + 0] = mu;
            stats1[(size_t)row * 3 + 1] = rstd;
            stats1[(size_t)row * 3 + 2] = invn;
        }
        invn = __shfl(invn, 0, 64);

        ushort_t* dst = (ushort_t*)x1n + (size_t)row * DIMN;
        #pragma unroll
        for (int j = 0; j < 4; ++j) {
            uint2 pk;
            pk.x = (unsigned)f2bf((float)(y[j * 4 + 0] * invn)) |
                   ((unsigned)f2bf((float)(y[j * 4 + 1] * invn)) << 16);
            pk.y = (unsigned)f2bf((float)(y[j * 4 + 2] * invn)) |
                   ((unsigned)f2bf((float)(y[j * 4 + 3] * invn)) << 16);
            *(uint2*)(dst + lane * 4 + j * 256) = pk;
        }
    } else {
        const int q = (bid - N1C / 4) * 4 + wave;
        const float* xr = clip + (size_t)q * DIMN;
        float4 xv[4];
        #pragma unroll
        for (int j = 0; j < 4; ++j)
            xv[j] = *(const float4*)(xr + lane * 4 + j * 256);

        double s = 0.0, s2 = 0.0;
        #pragma unroll
        for (int j = 0; j < 4; ++j) {
            double a = xv[j].x, b = xv[j].y, c = xv[j].z, d = xv[j].w;
            s += (a + b) + (c + d);
            s2 += (a * a + b * b) + (c * c + d * d);
        }
        s = wave_reduce_sum_d(s);
        s2 = wave_reduce_sum_d(s2);
        double mu, rstd;
        if (lane == 0) {
            mu = s / (double)DIMN;
            double var = s2 / (double)DIMN - mu * mu;
            rstd = 1.0 / sqrt(var + 1e-5);
        }
        mu = __shfl(mu, 0, 64);
        rstd = __shfl(rstd, 0, 64);

        double yv[16];
        double qq = 0.0;
        #pragma unroll
        for (int j = 0; j < 4; ++j) {
            const float4 g2v = *(const float4*)(g2 + lane * 4 + j * 256);
            const float4 b2v = *(const float4*)(b2 + lane * 4 + j * 256);
            double y0 = ((double)xv[j].x - mu) * rstd * (double)g2v.x + (double)b2v.x;
            double y1 = ((double)xv[j].y - mu) * rstd * (double)g2v.y + (double)b2v.y;
            double y2 = ((double)xv[j].z - mu) * rstd * (double)g2v.z + (double)b2v.z;
            double y3 = ((double)xv[j].w - mu) * rstd * (double)g2v.w + (double)b2v.w;
            yv[j * 4 + 0] = y0; yv[j * 4 + 1] = y1;
            yv[j * 4 + 2] = y2; yv[j * 4 + 3] = y3;
            qq += (y0 * y0 + y1 * y1) + (y2 * y2 + y3 * y3);
        }
        qq = wave_reduce_sum_d(qq);
        double invn;
        if (lane == 0) invn = 1.0 / fmax(sqrt(qq), 1e-8);
        invn = __shfl(invn, 0, 64);

        double c1 = 0.0, c2 = 0.0;
        ushort_t* dst = (ushort_t*)x2n + (size_t)q * DIMN;
        double* wrow = wq + (size_t)q * DIMN;
        #pragma unroll
        for (int j = 0; j < 4; ++j) {
            double y0 = yv[j * 4 + 0] * invn, y1 = yv[j * 4 + 1] * invn;
            double y2 = yv[j * 4 + 2] * invn, y3 = yv[j * 4 + 3] * invn;
            uint2 pk;
            pk.x = (unsigned)f2bf((float)y0) | ((unsigned)f2bf((float)y1) << 16);
            pk.y = (unsigned)f2bf((float)y2) | ((unsigned)f2bf((float)y3) << 16);
            *(uint2*)(dst + lane * 4 + j * 256) = pk;

            const float4 g1v = *(const float4*)(g1 + lane * 4 + j * 256);
            const float4 b1v = *(const float4*)(b1 + lane * 4 + j * 256);
            double w0 = y0 * (double)g1v.x, w1 = y1 * (double)g1v.y;
            double w2 = y2 * (double)g1v.z, w3 = y3 * (double)g1v.w;
            double* wp = wrow + lane * 4 + j * 256;
            double2 t0; t0.x = w0; t0.y = w1;
            double2 t1; t1.x = w2; t1.y = w3;
            *(double2*)(wp) = t0;
            *(double2*)(wp + 2) = t1;
            c1 += ((double)b1v.x * y0 + (double)b1v.y * y1) +
                  ((double)b1v.z * y2 + (double)b1v.w * y3);
            c2 += (w0 + w1) + (w2 + w3);
        }
        c1 = wave_reduce_sum_d(c1);
        c2 = wave_reduce_sum_d(c2);
        if (lane == 0) {
            consts[(size_t)q * 2 + 0] = c1;
            consts[(size_t)q * 2 + 1] = c2;
        }
    }
}

// ---------------------------------------------------------------------------
// Kernel 2: candidate GEMM, 256x256 tile, 8 waves, BK=32, triple-buffered
// LDS, counted vmcnt, setprio. NEW: XOR bank-swizzle via pre-swizzled
// GLOBAL source (LDS dest stays linear for gload_lds; read applies the same
// involution col^((row&3)*8) -> 8-way conflict reduced to 4-way).
// ---------------------------------------------------------------------------
#define BM2 256
#define BN2 256
#define BK2 32
#define NT2 (DIMN / BK2)

__global__ __launch_bounds__(512) void sim_gemm(
    const __hip_bfloat16* __restrict__ x2n, const __hip_bfloat16* __restrict__ x1n,
    ushort_t* __restrict__ simkey) {
    __shared__ __align__(16) ushort_t As2[3][BM2][BK2];   // 3 x 16 KB
    __shared__ __align__(16) ushort_t Bs2[3][BN2][BK2];   // 3 x 16 KB

    const int bid = blockIdx.x;
    const int l = (bid & 7) * 32 + (bid >> 3);
    const int q0 = (l & 1) * BM2;
    const int n0 = (l >> 1) * BN2;

    const int tid = threadIdx.x;
    const int ln = tid & 63, wv = tid >> 6;
    const int wr = wv >> 2, wc = wv & 3;

    const int st_r = ln >> 2;                       // row within 16-row chunk
    // swizzled global column: lane writing LDS col (ln&3)*8 fetches global
    // col ((ln&3)^(st_r&3))*8  (involution within the 64B row)
    const int st_c = (((ln & 3) ^ (st_r & 3)) * 8);

    const ushort_t* Ab = (const ushort_t*)x2n;
    const ushort_t* Bb = (const ushort_t*)x1n;

    f32x4 acc[8][4];
    #pragma unroll
    for (int m = 0; m < 8; ++m)
        #pragma unroll
        for (int n = 0; n < 4; ++n) acc[m][n] = (f32x4)0.0f;

    const int lr = ln & 15;
    const int lk0 = (ln >> 4) * 8;
    const int lk = lk0 ^ ((lr & 3) * 8);            // swizzled LDS read col

    // prologue: stage tiles 0 and 1 into buffers 0 and 1
    #pragma unroll
    for (int tt = 0; tt < 2; ++tt) {
        const int kt = tt * BK2;
        #pragma unroll
        for (int i = 0; i < 2; ++i) {
            int c = i * 8 + wv;
            int row = c * 16 + st_r;
            gload_lds16(Ab + (size_t)(q0 + row) * DIMN + kt + st_c,
                        (char*)&As2[tt][0][0] + c * 1024);
            gload_lds16(Bb + (size_t)(n0 + row) * DIMN + kt + st_c,
                        (char*)&Bs2[tt][0][0] + c * 1024);
        }
    }
    asm volatile("s_waitcnt vmcnt(4)" ::: "memory");
    __builtin_amdgcn_s_barrier();

    int cur = 0;
    #pragma unroll 1
    for (int t = 0; t < NT2; ++t) {
        short8 af[8], bfr[4];
        #pragma unroll
        for (int m = 0; m < 8; ++m)
            af[m] = *(const short8*)&As2[cur][wr * 128 + m * 16 + lr][lk];
        #pragma unroll
        for (int n = 0; n < 4; ++n)
            bfr[n] = *(const short8*)&Bs2[cur][wc * 64 + n * 16 + lr][lk];
        asm volatile("s_waitcnt lgkmcnt(0)" ::: "memory");
        __builtin_amdgcn_sched_barrier(0);

        if (t + 2 < NT2) {
            int stb = cur + 2; if (stb >= 3) stb -= 3;
            const int kt = (t + 2) * BK2;
            #pragma unroll
            for (int i = 0; i < 2; ++i) {
                int c = i * 8 + wv;
                int row = c * 16 + st_r;
                gload_lds16(Ab + (size_t)(q0 + row) * DIMN + kt + st_c,
                            (char*)&As2[stb][0][0] + c * 1024);
                gload_lds16(Bb + (size_t)(n0 + row) * DIMN + kt + st_c,
                            (char*)&Bs2[stb][0][0] + c * 1024);
            }
        }

        __builtin_amdgcn_s_setprio(1);
        #pragma unroll
        for (int m = 0; m < 8; ++m)
            #pragma unroll
            for (int n = 0; n < 4; ++n)
                acc[m][n] = __builtin_amdgcn_mfma_f32_16x16x32_bf16(
                    af[m], bfr[n], acc[m][n], 0, 0, 0);
        __builtin_amdgcn_s_setprio(0);

        if (t < NT2 - 1) {
            if (t < NT2 - 2)
                asm volatile("s_waitcnt vmcnt(4)" ::: "memory");
            else
                asm volatile("s_waitcnt vmcnt(0)" ::: "memory");
            __builtin_amdgcn_s_barrier();
        }
        cur = cur + 1; if (cur >= 3) cur -= 3;
    }

    const int crow = (ln >> 4) * 4;
    #pragma unroll
    for (int m = 0; m < 8; ++m) {
        #pragma unroll
        for (int n = 0; n < 4; ++n) {
            int col = n0 + wc * 64 + n * 16 + lr;
            #pragma unroll
            for (int r = 0; r < 4; ++r) {
                int row = q0 + wr * 128 + m * 16 + crow + r;
                simkey[(size_t)row * N1C + col] =
                    (ushort_t)key_of_bf16((unsigned)f2bf(acc[m][n][r]));
            }
        }
    }
}

// ---------------------------------------------------------------------------
// Kernel 3a: per-(q, segment) top->=MCAND via 2-pass RADIX-SELECT (R14).
// ---------------------------------------------------------------------------
__global__ __launch_bounds__(256) void seg_topk_rad(
    const ushort_t* __restrict__ simkey, unsigned* __restrict__ segcand,
    int* __restrict__ segcnt) {
    const int bid = blockIdx.x;
    const int seg = bid & 3, q = bid >> 2;
    const int tid = threadIdx.x;
    const int lane = tid & 63, wave = tid >> 6;

    __shared__ unsigned histA[256], histB[256];
    __shared__ unsigned scnt;
    __shared__ unsigned hb_sh, above_sh, lb_sh, dummy_sh;

    histA[tid] = 0;
    histB[tid] = 0;
    if (tid == 0) scnt = 0;

    const unsigned* rowPair =
        (const unsigned*)(simkey + (size_t)q * N1C) + seg * (SEG / 2);
    unsigned kreg[16];
    #pragma unroll
    for (int s = 0; s < 16; ++s)
        kreg[s] = rowPair[s * 256 + tid];
    __syncthreads();

    #pragma unroll
    for (int s = 0; s < 16; ++s) {
        atomicAdd(&histA[(kreg[s] >> 8) & 0xFFu], 1u);
        atomicAdd(&histA[kreg[s] >> 24], 1u);
    }
    __syncthreads();
    if (wave == 0) radix_scan_w0(histA, MCAND, lane, &hb_sh, &above_sh);
    __syncthreads();
    const unsigned hb = hb_sh;
    const unsigned need2 = MCAND - above_sh;

    #pragma unroll
    for (int s = 0; s < 16; ++s) {
        unsigned k0 = kreg[s] & 0xFFFFu, k1 = kreg[s] >> 16;
        if ((k0 >> 8) == hb) atomicAdd(&histB[k0 & 0xFFu], 1u);
        if ((k1 >> 8) == hb) atomicAdd(&histB[k1 & 0xFFu], 1u);
    }
    __syncthreads();
    if (wave == 0) radix_scan_w0(histB, need2, lane, &lb_sh, &dummy_sh);
    __syncthreads();
    const unsigned thr = (hb << 8) | lb_sh;

    #pragma unroll
    for (int s = 0; s < 16; ++s) {
        unsigned k0 = kreg[s] & 0xFFFFu, k1 = kreg[s] >> 16;
        unsigned e0 = (unsigned)(seg * SEG + (s * 256 + tid) * 2);
        if (k0 >= thr) {
            unsigned p = atomicAdd(&scnt, 1u);
            if (p < SEGCAP) segcand[(size_t)bid * SEGCAP + p] = (k0 << 16) | e0;
        }
        if (k1 >= thr) {
            unsigned p = atomicAdd(&scnt, 1u);
            if (p < SEGCAP) segcand[(size_t)bid * SEGCAP + p] = (k1 << 16) | (e0 + 1);
        }
    }
    __syncthreads();
    if (tid == 0) segcnt[bid] = (int)(scnt < SEGCAP ? scnt : SEGCAP);
}

// ---------------------------------------------------------------------------
// Kernel 3b: merge 4 segments' pools via the same 2-pass radix-select (R14).
// ---------------------------------------------------------------------------
__global__ __launch_bounds__(256) void merge_cand(
    const unsigned* __restrict__ segcand, const int* __restrict__ segcnt,
    int* __restrict__ cand, int* __restrict__ cand_cnt) {
    const int q = blockIdx.x;
    const int tid = threadIdx.x;
    const int lane = tid & 63, wave = tid >> 6;

    __shared__ unsigned buf[4 * SEGCAP];
    __shared__ int offs[5];
    __shared__ unsigned histA[256], histB[256];
    __shared__ unsigned cnt;
    __shared__ unsigned hb_sh, above_sh, lb_sh, dummy_sh;

    histA[tid] = 0;
    histB[tid] = 0;
    if (tid == 0) {
        int o = 0;
        #pragma unroll
        for (int s = 0; s < 4; ++s) { offs[s] = o; o += segcnt[q * 4 + s]; }
        offs[4] = o;
        cnt = 0;
    }
    __syncthreads();
    const int tot = offs[4];
    #pragma unroll
    for (int s = 0; s < 4; ++s) {
        int cs = offs[s + 1] - offs[s];
        for (int i = tid; i < cs; i += 256)
            buf[offs[s] + i] = segcand[(size_t)(q * 4 + s) * SEGCAP + i];
    }
    __syncthreads();

    unsigned e0 = 0, e1 = 0, e2 = 0, e3 = 0;
    const bool h0 = tid < tot, h1 = tid + 256 < tot,
               h2 = tid + 512 < tot, h3 = tid + 768 < tot;
    if (h0) e0 = buf[tid];
    if (h1) e1 = buf[tid + 256];
    if (h2) e2 = buf[tid + 512];
    if (h3) e3 = buf[tid + 768];

    if (h0) atomicAdd(&histA[e0 >> 24], 1u);
    if (h1) atomicAdd(&histA[e1 >> 24], 1u);
    if (h2) atomicAdd(&histA[e2 >> 24], 1u);
    if (h3) atomicAdd(&histA[e3 >> 24], 1u);
    __syncthreads();
    if (wave == 0) radix_scan_w0(histA, MCAND, lane, &hb_sh, &above_sh);
    __syncthreads();
    const unsigned hb = hb_sh;
    const unsigned need2 = MCAND - above_sh;

    if (h0 && (e0 >> 24) == hb) atomicAdd(&histB[(e0 >> 16) & 0xFFu], 1u);
    if (h1 && (e1 >> 24) == hb) atomicAdd(&histB[(e1 >> 16) & 0xFFu], 1u);
    if (h2 && (e2 >> 24) == hb) atomicAdd(&histB[(e2 >> 16) & 0xFFu], 1u);
    if (h3 && (e3 >> 24) == hb) atomicAdd(&histB[(e3 >> 16) & 0xFFu], 1u);
    __syncthreads();
    if (wave == 0) radix_scan_w0(histB, need2, lane, &lb_sh, &dummy_sh);
    __syncthreads();
    const unsigned thr = (hb << 8) | lb_sh;

    if (h0 && (e0 >> 16) >= thr) {
        unsigned p = atomicAdd(&cnt, 1u);
        if (p < CAP) cand[(size_t)q * CAP + p] = (int)(e0 & 0xFFFFu);
    }
    if (h1 && (e1 >> 16) >= thr) {
        unsigned p = atomicAdd(&cnt, 1u);
        if (p < CAP) cand[(size_t)q * CAP + p] = (int)(e1 & 0xFFFFu);
    }
    if (h2 && (e2 >> 16) >= thr) {
        unsigned p = atomicAdd(&cnt, 1u);
        if (p < CAP) cand[(size_t)q * CAP + p] = (int)(e2 & 0xFFFFu);
    }
    if (h3 && (e3 >> 16) >= thr) {
        unsigned p = atomicAdd(&cnt, 1u);
        if (p < CAP) cand[(size_t)q * CAP + p] = (int)(e3 & 0xFFFFu);
    }
    __syncthreads();
    if (tid == 0) cand_cnt[q] = (int)(cnt < CAP ? cnt : CAP);
}

// ---------------------------------------------------------------------------
// Kernel 4a: fp64 factorized scoring, 4 candidates in flight per wave.
// ---------------------------------------------------------------------------
__global__ __launch_bounds__(256) void score_cand(
    const float* __restrict__ x1, const double* __restrict__ stats1,
    const double* __restrict__ wq, const double* __restrict__ consts,
    const int* __restrict__ cand, const int* __restrict__ cand_cnt,
    double* __restrict__ vals) {
    const int q = blockIdx.x, chunk = blockIdx.y;
    const int tid = threadIdx.x;
    const int lane = tid & 63, wv = tid >> 6;
    const int cnt = cand_cnt[q];
    const int cbase = chunk * 16;
    if (cbase >= cnt) return;

    const double C1 = consts[(size_t)q * 2 + 0];
    const double C2 = consts[(size_t)q * 2 + 1];

    const double* w = wq + (size_t)q * DIMN;
    double wr[16];
    #pragma unroll
    for (int j = 0; j < 4; ++j) {
        double2 a = *(const double2*)(w + lane * 4 + j * 256);
        double2 b = *(const double2*)(w + lane * 4 + j * 256 + 2);
        wr[j * 4 + 0] = a.x; wr[j * 4 + 1] = a.y;
        wr[j * 4 + 2] = b.x; wr[j * 4 + 3] = b.y;
    }

    const int cA = cbase + wv;
    const int cB = cA + 4;
    const int cC = cA + 8;
    const int cD = cA + 12;
    const bool hA = cA < cnt, hB = cB < cnt, hC = cC < cnt, hD = cD < cnt;
    if (!hA) return;
    const int nA = cand[(size_t)q * CAP + cA];
    const int nB = hB ? cand[(size_t)q * CAP + cB] : nA;
    const int nC = hC ? cand[(size_t)q * CAP + cC] : nA;
    const int nD = hD ? cand[(size_t)q * CAP + cD] : nA;
    const float* xrA = x1 + (size_t)nA * DIMN;
    const float* xrB = x1 + (size_t)nB * DIMN;
    const float* xrC = x1 + (size_t)nC * DIMN;
    const float* xrD = x1 + (size_t)nD * DIMN;

    double aA = 0.0, aB = 0.0, aC = 0.0, aD = 0.0;
    #pragma unroll
    for (int j = 0; j < 4; ++j) {
        float4 xa = *(const float4*)(xrA + lane * 4 + j * 256);
        float4 xb = *(const float4*)(xrB + lane * 4 + j * 256);
        float4 xc = *(const float4*)(xrC + lane * 4 + j * 256);
        float4 xd = *(const float4*)(xrD + lane * 4 + j * 256);
        aA += (double)xa.x * wr[j * 4 + 0] + (double)xa.y * wr[j * 4 + 1] +
              (double)xa.z * wr[j * 4 + 2] + (double)xa.w * wr[j * 4 + 3];
        aB += (double)xb.x * wr[j * 4 + 0] + (double)xb.y * wr[j * 4 + 1] +
              (double)xb.z * wr[j * 4 + 2] + (double)xb.w * wr[j * 4 + 3];
        aC += (double)xc.x * wr[j * 4 + 0] + (double)xc.y * wr[j * 4 + 1] +
              (double)xc.z * wr[j * 4 + 2] + (double)xc.w * wr[j * 4 + 3];
        aD += (double)xd.x * wr[j * 4 + 0] + (double)xd.y * wr[j * 4 + 1] +
              (double)xd.z * wr[j * 4 + 2] + (double)xd.w * wr[j * 4 + 3];
    }
    aA = wave_reduce_sum_d(aA);
    aB = wave_reduce_sum_d(aB);
    aC = wave_reduce_sum_d(aC);
    aD = wave_reduce_sum_d(aD);
    if (lane == 0) {
        {
            const double mu1 = stats1[(size_t)nA * 3 + 0];
            const double rstd1 = stats1[(size_t)nA * 3 + 1];
            const double invn1 = stats1[(size_t)nA * 3 + 2];
            vals[(size_t)q * CAP + cA] = (rstd1 * invn1) * (aA - mu1 * C2) + invn1 * C1;
        }
        if (hB) {
            const double mu1 = stats1[(size_t)nB * 3 + 0];
            const double rstd1 = stats1[(size_t)nB * 3 + 1];
            const double invn1 = stats1[(size_t)nB * 3 + 2];
            vals[(size_t)q * CAP + cB] = (rstd1 * invn1) * (aB - mu1 * C2) + invn1 * C1;
        }
        if (hC) {
            const double mu1 = stats1[(size_t)nC * 3 + 0];
            const double rstd1 = stats1[(size_t)nC * 3 + 1];
            const double invn1 = stats1[(size_t)nC * 3 + 2];
            vals[(size_t)q * CAP + cC] = (rstd1 * invn1) * (aC - mu1 * C2) + invn1 * C1;
        }
        if (hD) {
            const double mu1 = stats1[(size_t)nD * 3 + 0];
            const double rstd1 = stats1[(size_t)nD * 3 + 1];
            const double invn1 = stats1[(size_t)nD * 3 + 2];
            vals[(size_t)q * CAP + cD] = (rstd1 * invn1) * (aD - mu1 * C2) + invn1 * C1;
        }
    }
}

// ---------------------------------------------------------------------------
// Kernel 4b: exact top-64 selection (value desc, idx asc). One wave per q.
// ---------------------------------------------------------------------------
__global__ __launch_bounds__(64) void select_topk(
    const double* __restrict__ vals, const int* __restrict__ cand,
    const int* __restrict__ cand_cnt, float* __restrict__ out) {
    const int q = blockIdx.x;
    const int lane = threadIdx.x;
    const int cnt = cand_cnt[q];

    double v0 = (lane < cnt)       ? vals[(size_t)q * CAP + lane]       : -1e300;
    double v1 = (lane + 64 < cnt)  ? vals[(size_t)q * CAP + lane + 64]  : -1e300;
    double v2 = (lane + 128 < cnt) ? vals[(size_t)q * CAP + lane + 128] : -1e300;
    double v3 = (lane + 192 < cnt) ? vals[(size_t)q * CAP + lane + 192] : -1e300;
    int i0 = (lane < cnt)       ? cand[(size_t)q * CAP + lane]       : 0x7FFFFFFF;
    int i1 = (lane + 64 < cnt)  ? cand[(size_t)q * CAP + lane + 64]  : 0x7FFFFFFF;
    int i2 = (lane + 128 < cnt) ? cand[(size_t)q * CAP + lane + 128] : 0x7FFFFFFF;
    int i3 = (lane + 192 < cnt) ? cand[(size_t)q * CAP + lane + 192] : 0x7FFFFFFF;

    for (int k = 0; k < KTOP; ++k) {
        bool a01 = (v0 > v1) || (v0 == v1 && i0 < i1);
        double va = a01 ? v0 : v1; int ia = a01 ? i0 : i1; int sa = a01 ? 0 : 1;
        bool a23 = (v2 > v3) || (v2 == v3 && i2 < i3);
        double vb = a23 ? v2 : v3; int ib = a23 ? i2 : i3; int sb = a23 ? 2 : 3;
        bool ab = (va > vb) || (va == vb && ia < ib);
        double mv = ab ? va : vb; int mi = ab ? ia : ib; int slot = ab ? sa : sb;
        int owner = lane;
        #pragma unroll
        for (int off = 32; off > 0; off >>= 1) {
            double ov = __shfl_down(mv, off, 64);
            int oi = __shfl_down(mi, off, 64);
            int oo = __shfl_down(owner, off, 64);
            int os = __shfl_down(slot, off, 64);
            bool take = (ov > mv) || (ov == mv && oi < mi);
            if (take) { mv = ov; mi = oi; owner = oo; slot = os; }
        }
        int wown = __shfl(owner, 0, 64);
        int wslot = __shfl(slot, 0, 64);
        int wmi = __shfl(mi, 0, 64);
        if (lane == 0) out[(size_t)q * KTOP + k] = (float)wmi * (1.0f / 32768.0f);
        if (lane == wown) {
            v0 = (wslot == 0) ? -1e300 : v0;
            v1 = (wslot == 1) ? -1e300 : v1;
            v2 = (wslot == 2) ? -1e300 : v2;
            v3 = (wslot == 3) ? -1e300 : v3;
        }
    }
}

// ---------------------------------------------------------------------------
extern "C" void kernel_launch(void* const* d_in, const int* in_sizes, int n_in,
                              void* d_out, int out_size, void* d_ws, size_t ws_size,
                              hipStream_t stream) {
    const float* prior = (const float*)d_in[0];
    const float* clip  = (const float*)d_in[1];
    const float* g1    = (const float*)d_in[2];
    const float* b1    = (const float*)d_in[3];
    const float* g2    = (const float*)d_in[4];
    const float* b2    = (const float*)d_in[5];
    float* out = (float*)d_out;

    char* ws = (char*)d_ws;
    size_t off = 0;
    double* stats1 = (double*)(ws + off); off += (size_t)N1C * 3 * sizeof(double);
    __hip_bfloat16* x1n = (__hip_bfloat16*)(ws + off); off += (size_t)N1C * DIMN * 2;
    __hip_bfloat16* x2n = (__hip_bfloat16*)(ws + off); off += (size_t)N2C * DIMN * 2;
    ushort_t* simkey = (ushort_t*)(ws + off); off += (size_t)N2C * N1C * 2;
    unsigned* segcand = (unsigned*)(ws + off); off += (size_t)N2C * 4 * SEGCAP * 4;
    int* segcnt = (int*)(ws + off); off += (size_t)N2C * 4 * sizeof(int);
    int* cand = (int*)(ws + off); off += (size_t)N2C * CAP * sizeof(int);
    int* cand_cnt = (int*)(ws + off); off += (size_t)N2C * sizeof(int);
    double* wq = (double*)(ws + off); off += (size_t)N2C * DIMN * sizeof(double);
    double* consts = (double*)(ws + off); off += (size_t)N2C * 2 * sizeof(double);
    double* vals = (double*)(ws + off); off += (size_t)N2C * CAP * sizeof(double);

    ln_all<<<N1C / 4 + N2C / 4, 256, 0, stream>>>(
        prior, clip, g1, b1, g2, b2, x1n, x2n, stats1, wq, consts);

    sim_gemm<<<(N1C / BN2) * (N2C / BM2), 512, 0, stream>>>(x2n, x1n, simkey);

    seg_topk_rad<<<N2C * 4, 256, 0, stream>>>(simkey, segcand, segcnt);
    merge_cand<<<N2C, 256, 0, stream>>>(segcand, segcnt, cand, cand_cnt);

    dim3 gs(N2C, 16);
    score_cand<<<gs, 256, 0, stream>>>(prior, stats1, wq, consts, cand, cand_cnt, vals);
    select_topk<<<N2C, 64, 0, stream>>>(vals, cand, cand_cnt, out);
}